// Round 21
// baseline (537.405 us; speedup 1.0000x reference)
//
#include <hip/hip_runtime.h>
#include <cmath>

#define D_MODEL 1024
#define D_STATE 16
#define D_INNER 2048
#define NB 4
#define SEQL 2048
#define ROWS (NB*SEQL)        // 8192
#define XZ_LD (2*D_INNER)     // 4096

typedef __attribute__((ext_vector_type(8))) short short8;
typedef __attribute__((ext_vector_type(4))) float f32x4;

__device__ __forceinline__ float sigmoidf_(float v) { return 1.0f / (1.0f + __expf(-v)); }

__device__ __forceinline__ unsigned short bf16rne(float f) {
    unsigned u = __float_as_uint(f);
    unsigned r = (u + 0x7FFFu + ((u >> 16) & 1u)) >> 16;
    return (unsigned short)r;
}

// ---------------- fp32 -> bf16 ----------------
__global__ __launch_bounds__(256) void pack1_k(const float4* __restrict__ in,
    ushort4* __restrict__ out, int n4)
{
    int i = blockIdx.x * 256 + threadIdx.x;
    if (i >= n4) return;
    float4 v = in[i];
    ushort4 h;
    h.x = bf16rne(v.x); h.y = bf16rne(v.y); h.z = bf16rne(v.z); h.w = bf16rne(v.w);
    out[i] = h;
}

// ============ 8-phase-style bf16 NT GEMM (round-10 schedule, verbatim) ============
// BM=128 for BOTH GEMMs now: 72 KB LDS -> 2 blocks/CU, cross-block overlap hides the
// per-phase barrier/vmcnt stalls (BM=256's 96 KB -> 1 block/CU had no partner; m114).
#define GLDS(gp, lp) __builtin_amdgcn_global_load_lds( \
    (const __attribute__((address_space(1))) void*)(gp), \
    (__attribute__((address_space(3))) void*)(lp), 16, 0, 0)

extern __shared__ __align__(16) unsigned short smem8[];

template<int BM>
__global__ __launch_bounds__(512, 2) void gemm8p(
    const unsigned short* __restrict__ A2, int lda,
    const unsigned short* __restrict__ B2, int ldb,
    float* __restrict__ C, int ldc, int K)
{
    constexpr int APAN = BM * 32;
    constexpr int BPAN = 256 * 32;
    constexpr int LA   = BM / 128;
    constexpr int MH   = BM / 128;
    constexpr int WROW = (BM == 256) ? 128 : 64;
    unsigned short* sA = smem8;
    unsigned short* sB = smem8 + 3 * APAN;

    const int tid = threadIdx.x;
    const int bm = blockIdx.y * BM, bn = blockIdx.x * 256;
    const int wave = tid >> 6, lane = tid & 63;
    const int wm = wave >> 2, wn = wave & 3;
    const int fr = lane & 15, kq = lane >> 4;
    const int NT = K >> 5;

    size_t offA[LA], offB[2];
#pragma unroll
    for (int i = 0; i < LA; ++i) {
        int c = i * 512 + tid;
        int row = c & (BM - 1), slot = (BM == 256) ? (c >> 8) : (c >> 7);
        offA[i] = (size_t)(bm + row) * lda + slot * 8;
    }
#pragma unroll
    for (int i = 0; i < 2; ++i) {
        int c = i * 512 + tid;
        int row = c & 255, slot = c >> 8;
        offB[i] = (size_t)(bn + row) * ldb + slot * 8;
    }

    auto stageA = [&](int s) {
        int ka = s * 32;
        unsigned short* d = sA + (s % 3) * APAN;
#pragma unroll
        for (int i = 0; i < LA; ++i)
            GLDS(A2 + offA[i] + ka, d + (i * 512 + tid) * 8);
    };
    auto stageB = [&](int s) {
        int kb = s * 32;
        unsigned short* d = sB + (s % 3) * BPAN;
#pragma unroll
        for (int i = 0; i < 2; ++i)
            GLDS(B2 + offB[i] + kb, d + (i * 512 + tid) * 8);
    };

    f32x4 acc[4 * MH][4];
#pragma unroll
    for (int m = 0; m < 4 * MH; ++m)
#pragma unroll
        for (int n = 0; n < 4; ++n) acc[m][n] = (f32x4){0.f, 0.f, 0.f, 0.f};

    stageA(0); stageB(0); stageA(1); stageB(1);
    if constexpr (BM == 256) asm volatile("s_waitcnt vmcnt(4)" ::: "memory");
    else                     asm volatile("s_waitcnt vmcnt(3)" ::: "memory");
    __builtin_amdgcn_s_barrier();
    asm volatile("" ::: "memory");

    for (int t = 0; t < NT; ++t) {
        const unsigned short* pA = sA + (t % 3) * APAN;
        const unsigned short* pB = sB + (t % 3) * BPAN;
        short8 b0[4], a0[4];
#pragma unroll
        for (int n = 0; n < 4; ++n)
            b0[n] = *(const short8*)&pB[(kq * 256 + wn * 64 + n * 16 + fr) * 8];
#pragma unroll
        for (int m = 0; m < 4; ++m)
            a0[m] = *(const short8*)&pA[(kq * BM + wm * WROW + m * 16 + fr) * 8];
        if (t + 2 < NT) stageA(t + 2);
        if constexpr (MH == 1) { if (t + 2 < NT) stageB(t + 2); }
        __builtin_amdgcn_s_barrier();
        asm volatile("" ::: "memory");
        __builtin_amdgcn_s_setprio(1);
#pragma unroll
        for (int m = 0; m < 4; ++m)
#pragma unroll
            for (int n = 0; n < 4; ++n)
                acc[m][n] = __builtin_amdgcn_mfma_f32_16x16x32_bf16(a0[m], b0[n], acc[m][n], 0, 0, 0);
        __builtin_amdgcn_s_setprio(0);
        if constexpr (MH == 2) {
            __builtin_amdgcn_s_barrier();
            asm volatile("" ::: "memory");
            short8 a1[4];
#pragma unroll
            for (int m = 0; m < 4; ++m)
                a1[m] = *(const short8*)&pA[(kq * 256 + wm * 128 + 64 + m * 16 + fr) * 8];
            if (t + 2 < NT) stageB(t + 2);
            __builtin_amdgcn_s_barrier();
            asm volatile("" ::: "memory");
            __builtin_amdgcn_s_setprio(1);
#pragma unroll
            for (int m = 0; m < 4; ++m)
#pragma unroll
                for (int n = 0; n < 4; ++n)
                    acc[4 + m][n] = __builtin_amdgcn_mfma_f32_16x16x32_bf16(a1[m], b0[n], acc[4 + m][n], 0, 0, 0);
            __builtin_amdgcn_s_setprio(0);
        }
        if (t + 2 < NT) {
            if constexpr (BM == 256) asm volatile("s_waitcnt vmcnt(4)" ::: "memory");
            else                     asm volatile("s_waitcnt vmcnt(3)" ::: "memory");
        } else if (t + 1 < NT) {
            asm volatile("s_waitcnt vmcnt(0)" ::: "memory");
        }
        __builtin_amdgcn_s_barrier();
        asm volatile("" ::: "memory");
    }

    // C/D layout: col = lane&15, row = (lane>>4)*4 + j
#pragma unroll
    for (int mm = 0; mm < 4 * MH; ++mm) {
        int row0 = bm + wm * WROW + mm * 16 + kq * 4;
#pragma unroll
        for (int j = 0; j < 4; ++j) {
            float* Cr = C + (size_t)(row0 + j) * ldc + bn + wn * 64 + fr;
#pragma unroll
            for (int n = 0; n < 4; ++n) Cr[n * 16] = acc[mm][n][j];
        }
    }
}

// ---------------- causal depthwise conv (D_CONV=4) + SiLU ----------------
__global__ __launch_bounds__(256) void conv_silu_k(
    const float* __restrict__ xz, const float* __restrict__ conv_w,
    const float* __restrict__ conv_b, float* __restrict__ x_conv)
{
    int idx = blockIdx.x * 256 + threadIdx.x;   // ROWS * 512 total
    int q = idx & 511;
    int r = idx >> 9;
    int b = r >> 11, t = r & (SEQL - 1);
    int d0 = q << 2;
    float w[4][4];
#pragma unroll
    for (int c = 0; c < 4; ++c) *(float4*)w[c] = *(const float4*)&conv_w[(d0 + c) * 4];
    float4 acc = *(const float4*)&conv_b[d0];
    const float* xp = xz + (size_t)(b * SEQL) * XZ_LD + d0;
#pragma unroll
    for (int k = 0; k < 4; ++k) {
        int t2 = t - 3 + k;
        if (t2 >= 0) {
            float4 v = *(const float4*)(xp + (size_t)t2 * XZ_LD);
            acc.x = fmaf(v.x, w[0][k], acc.x);
            acc.y = fmaf(v.y, w[1][k], acc.y);
            acc.z = fmaf(v.z, w[2][k], acc.z);
            acc.w = fmaf(v.w, w[3][k], acc.w);
        }
    }
    acc.x *= sigmoidf_(acc.x);
    acc.y *= sigmoidf_(acc.y);
    acc.z *= sigmoidf_(acc.z);
    acc.w *= sigmoidf_(acc.w);
    *(float4*)&x_conv[(size_t)r * D_INNER + d0] = acc;
}

// ---- x_proj -> A_bar/B_bar/C, normal [row][s] layout (coalesced scan staging) ----
__global__ __launch_bounds__(256) void proj_k(
    const float* __restrict__ x_conv, const float* __restrict__ W_xproj,
    const float* __restrict__ A_log,
    float* __restrict__ Abar, float* __restrict__ Bbar, float* __restrict__ Cmat)
{
    __shared__ float sdbl[4][33];
    int tid = threadIdx.x;
    int w = tid >> 6, lane = tid & 63;
    int row = blockIdx.x * 4 + w;
    const float* xrow = x_conv + (size_t)row * D_INNER;
    float4 xr[8];
#pragma unroll
    for (int it = 0; it < 8; ++it)
        xr[it] = *(const float4*)&xrow[it * 256 + lane * 4];

    for (int j = 0; j < 33; ++j) {
        const float* wrow = W_xproj + j * D_INNER;
        float accv = 0.f;
#pragma unroll
        for (int it = 0; it < 8; ++it) {
            float4 wv = *(const float4*)&wrow[it * 256 + lane * 4];
            accv = fmaf(xr[it].x, wv.x, accv);
            accv = fmaf(xr[it].y, wv.y, accv);
            accv = fmaf(xr[it].z, wv.z, accv);
            accv = fmaf(xr[it].w, wv.w, accv);
        }
#pragma unroll
        for (int off = 32; off; off >>= 1) accv += __shfl_xor(accv, off);
        if (lane == 0) sdbl[w][j] = accv;
    }
    __syncthreads();
    if (tid < 64) {
        int w2 = tid >> 4, s = tid & 15;
        int row2 = blockIdx.x * 4 + w2;
        float draw = sdbl[w2][32];
        float sp = (draw > 20.f) ? draw : log1pf(__expf(draw));
        float dt = fminf(fmaxf(sp, 0.001f), 0.1f);
        float Aa = -__expf(A_log[s]);
        float dtA = fminf(fmaxf(dt * Aa, -20.f), 0.f);
        Abar[row2 * 16 + s] = __expf(dtA);
        float bb = dt * sdbl[w2][s];
        Bbar[row2 * 16 + s] = fminf(fmaxf(bb, -10.f), 10.f);
        Cmat[row2 * 16 + s] = sdbl[w2][16 + s];
    }
}

// ---------------- SSM scan: round-19 monolithic (measured 177 us) ----------------
#define SCH 16
#define TT 16
__global__ __launch_bounds__(256) void scan_k(
    const float* __restrict__ x_conv, const float* __restrict__ xz,
    unsigned short* __restrict__ yhl,
    const float* __restrict__ Abar, const float* __restrict__ Bbar,
    const float* __restrict__ Cmat, const float* __restrict__ D_param)
{
    __shared__ __align__(16) float sXa[2][SCH][20];
    __shared__ float sZp[2][SCH][17];
    __shared__ __align__(16) float sPa[2][16][20];
    __shared__ __align__(16) float sPb[2][16][20];
    __shared__ __align__(16) float sPc[2][16][20];
    __shared__ __align__(16) float sT[SCH][328];

    const int tid = threadIdx.x;
    const int b = blockIdx.y, dbase = blockIdx.x * SCH;
    const int chl = tid >> 4, s = tid & 15;
    const float* xc = x_conv + (size_t)(b * SEQL) * D_INNER + dbase;
    const float* zp = xz + (size_t)(b * SEQL) * XZ_LD + D_INNER + dbase;
    const int pbase0 = (b * SEQL) * 16;
    const int st = tid >> 4, sc = tid & 15;

    auto stage = [&](int buf, int tc) {
        int t0 = tc * TT;
        sXa[buf][sc][st] = xc[(size_t)(t0 + st) * D_INNER + sc];
        sZp[buf][sc][st] = zp[(size_t)(t0 + st) * XZ_LD + sc];
        int g = pbase0 + t0 * 16 + tid;
        sPa[buf][sc][st] = Abar[g];
        sPb[buf][sc][st] = Bbar[g];
        sPc[buf][sc][st] = Cmat[g];
    };

    stage(0, 0);
    float h = 0.f;
    const float Dp = D_param[dbase + chl];

    for (int tc = 0; tc < SEQL / TT; ++tc) {
        int buf = tc & 1;
        int t0 = tc * TT;
        __syncthreads();
        if (tc + 1 < SEQL / TT) stage(buf ^ 1, tc + 1);

        float p[16];
#pragma unroll
        for (int q = 0; q < 4; ++q) {
            float4 a4 = *(const float4*)&sPa[buf][s][q * 4];
            float4 b4 = *(const float4*)&sPb[buf][s][q * 4];
            float4 c4 = *(const float4*)&sPc[buf][s][q * 4];
            float4 x4 = *(const float4*)&sXa[buf][chl][q * 4];
            h = fminf(fmaxf(fmaf(b4.x, x4.x, a4.x * h), -100.f), 100.f); p[q * 4 + 0] = h * c4.x;
            h = fminf(fmaxf(fmaf(b4.y, x4.y, a4.y * h), -100.f), 100.f); p[q * 4 + 1] = h * c4.y;
            h = fminf(fmaxf(fmaf(b4.z, x4.z, a4.z * h), -100.f), 100.f); p[q * 4 + 2] = h * c4.z;
            h = fminf(fmaxf(fmaf(b4.w, x4.w, a4.w * h), -100.f), 100.f); p[q * 4 + 3] = h * c4.w;
        }

#pragma unroll
        for (int i = 0; i < 16; ++i) sT[chl][i * 20 + s] = p[i];
        float4 r0 = *(const float4*)&sT[chl][s * 20 + 0];
        float4 r1 = *(const float4*)&sT[chl][s * 20 + 4];
        float4 r2 = *(const float4*)&sT[chl][s * 20 + 8];
        float4 r3 = *(const float4*)&sT[chl][s * 20 + 12];
        float ysum = ((r0.x + r1.x + r2.x + r3.x) + (r0.y + r1.y + r2.y + r3.y))
                   + ((r0.z + r1.z + r2.z + r3.z) + (r0.w + r1.w + r2.w + r3.w));

        float z = sZp[buf][chl][s];
        float x = sXa[buf][chl][s];
        float o = fmaf(x, Dp, ysum * (z * sigmoidf_(z)));
        size_t r = (size_t)(b * SEQL + t0 + s);
        yhl[r * 2 * XZ_LD + dbase + chl] = bf16rne(o);
    }
}

extern "C" void kernel_launch(void* const* d_in, const int* in_sizes, int n_in,
                              void* d_out, int out_size, void* d_ws, size_t ws_size,
                              hipStream_t stream) {
    const float* x       = (const float*)d_in[0];
    const float* W_in    = (const float*)d_in[1];
    const float* conv_w  = (const float*)d_in[2];
    const float* conv_b  = (const float*)d_in[3];
    const float* W_xproj = (const float*)d_in[4];
    const float* A_log   = (const float*)d_in[5];
    const float* D_param = (const float*)d_in[6];
    const float* W_out   = (const float*)d_in[7];
    float* out = (float*)d_out;

    // ---- workspace: round-1 footprint (202.9 MB), phase-aliased ----
    char* p = (char*)d_ws;
    char* xzB = p;
    float* xz = (float*)xzB;                 // 134.2 MB; rows: [x_proj | z] fp32
    p += (size_t)ROWS * XZ_LD * 4;
    char* xcB = p;
    float* x_conv = (float*)xcB;             // 67.1 MB
    p += (size_t)ROWS * D_INNER * 4;
    float* Abar = (float*)p; p += (size_t)ROWS * 16 * 4;
    float* Bbar = (float*)p; p += (size_t)ROWS * 16 * 4;
    float* Cm   = (float*)p; p += (size_t)ROWS * 16 * 4;

    unsigned short* x1  = (unsigned short*)xcB;
    unsigned short* Wi1 = x1 + (size_t)ROWS * D_MODEL;
    unsigned short* Wo1 = (unsigned short*)xcB;
    unsigned short* yhl = (unsigned short*)xzB;

    constexpr int SM2 = (3 * 128 * 32 + 3 * 256 * 32) * 2;   // 72 KiB

    // 0) pack x, W_in -> bf16
    pack1_k<<<ROWS * D_MODEL / 4 / 256, 256, 0, stream>>>(
        (const float4*)x, (ushort4*)x1, ROWS * D_MODEL / 4);
    pack1_k<<<2 * D_INNER * D_MODEL / 4 / 256, 256, 0, stream>>>(
        (const float4*)W_in, (ushort4*)Wi1, 2 * D_INNER * D_MODEL / 4);
    // 1) xz = x @ W_in^T  (M=8192, N=4096, K=1024); BM=128, grid (16, 64) = 1024 blocks,
    //    72 KB LDS -> 2 blocks/CU (was BM=256, 96 KB -> 1 block/CU, no overlap partner)
    gemm8p<128><<<dim3(4096 / 256, ROWS / 128), 512, SM2, stream>>>(
        x1, D_MODEL, Wi1, D_MODEL, xz, XZ_LD, D_MODEL);
    // 2) conv + silu
    conv_silu_k<<<ROWS * 512 / 256, 256, 0, stream>>>(xz, conv_w, conv_b, x_conv);
    // 3) x_proj
    proj_k<<<ROWS / 4, 256, 0, stream>>>(x_conv, W_xproj, A_log, Abar, Bbar, Cm);
    // 4) scan -> yh bf16 into xz rows' first half
    scan_k<<<dim3(D_INNER / SCH, NB), 256, 0, stream>>>(
        x_conv, xz, yhl, Abar, Bbar, Cm, D_param);
    // 5) pack W_out
    pack1_k<<<D_MODEL * D_INNER / 4 / 256, 256, 0, stream>>>(
        (const float4*)W_out, (ushort4*)Wo1, D_MODEL * D_INNER / 4);
    // 6) out = y @ W_out^T  (M=8192, N=1024, K=2048)
    gemm8p<128><<<dim3(1024 / 256, ROWS / 128), 512, SM2, stream>>>(
        yhl, 2 * XZ_LD, Wo1, D_INNER, out, D_MODEL, D_INNER);
}

// Round 22
// 475.245 us; speedup vs baseline: 1.1308x; 1.1308x over previous
//
#include <hip/hip_runtime.h>
#include <cmath>

#define D_MODEL 1024
#define D_STATE 16
#define D_INNER 2048
#define NB 4
#define SEQL 2048
#define ROWS (NB*SEQL)        // 8192
#define XZ_LD (2*D_INNER)     // 4096

typedef __attribute__((ext_vector_type(8))) short short8;
typedef __attribute__((ext_vector_type(4))) float f32x4;

__device__ __forceinline__ float sigmoidf_(float v) { return 1.0f / (1.0f + __expf(-v)); }

__device__ __forceinline__ unsigned short bf16rne(float f) {
    unsigned u = __float_as_uint(f);
    unsigned r = (u + 0x7FFFu + ((u >> 16) & 1u)) >> 16;
    return (unsigned short)r;
}
__device__ __forceinline__ float bf2f(unsigned short u) {
    return __uint_as_float((unsigned)u << 16);
}

// ---------------- fp32 -> bf16 ----------------
__global__ __launch_bounds__(256) void pack1_k(const float4* __restrict__ in,
    ushort4* __restrict__ out, int n4)
{
    int i = blockIdx.x * 256 + threadIdx.x;
    if (i >= n4) return;
    float4 v = in[i];
    ushort4 h;
    h.x = bf16rne(v.x); h.y = bf16rne(v.y); h.z = bf16rne(v.z); h.w = bf16rne(v.w);
    out[i] = h;
}

// ============ 8-phase-style bf16 NT GEMM (round-10 schedule, verbatim) ============
#define GLDS(gp, lp) __builtin_amdgcn_global_load_lds( \
    (const __attribute__((address_space(1))) void*)(gp), \
    (__attribute__((address_space(3))) void*)(lp), 16, 0, 0)

extern __shared__ __align__(16) unsigned short smem8[];

template<int BM>
__global__ __launch_bounds__(512, 2) void gemm8p(
    const unsigned short* __restrict__ A2, int lda,
    const unsigned short* __restrict__ B2, int ldb,
    float* __restrict__ C, int ldc, int K)
{
    constexpr int APAN = BM * 32;
    constexpr int BPAN = 256 * 32;
    constexpr int LA   = BM / 128;
    constexpr int MH   = BM / 128;
    constexpr int WROW = (BM == 256) ? 128 : 64;
    unsigned short* sA = smem8;
    unsigned short* sB = smem8 + 3 * APAN;

    const int tid = threadIdx.x;
    const int bm = blockIdx.y * BM, bn = blockIdx.x * 256;
    const int wave = tid >> 6, lane = tid & 63;
    const int wm = wave >> 2, wn = wave & 3;
    const int fr = lane & 15, kq = lane >> 4;
    const int NT = K >> 5;

    size_t offA[LA], offB[2];
#pragma unroll
    for (int i = 0; i < LA; ++i) {
        int c = i * 512 + tid;
        int row = c & (BM - 1), slot = (BM == 256) ? (c >> 8) : (c >> 7);
        offA[i] = (size_t)(bm + row) * lda + slot * 8;
    }
#pragma unroll
    for (int i = 0; i < 2; ++i) {
        int c = i * 512 + tid;
        int row = c & 255, slot = c >> 8;
        offB[i] = (size_t)(bn + row) * ldb + slot * 8;
    }

    auto stageA = [&](int s) {
        int ka = s * 32;
        unsigned short* d = sA + (s % 3) * APAN;
#pragma unroll
        for (int i = 0; i < LA; ++i)
            GLDS(A2 + offA[i] + ka, d + (i * 512 + tid) * 8);
    };
    auto stageB = [&](int s) {
        int kb = s * 32;
        unsigned short* d = sB + (s % 3) * BPAN;
#pragma unroll
        for (int i = 0; i < 2; ++i)
            GLDS(B2 + offB[i] + kb, d + (i * 512 + tid) * 8);
    };

    f32x4 acc[4 * MH][4];
#pragma unroll
    for (int m = 0; m < 4 * MH; ++m)
#pragma unroll
        for (int n = 0; n < 4; ++n) acc[m][n] = (f32x4){0.f, 0.f, 0.f, 0.f};

    stageA(0); stageB(0); stageA(1); stageB(1);
    if constexpr (BM == 256) asm volatile("s_waitcnt vmcnt(4)" ::: "memory");
    else                     asm volatile("s_waitcnt vmcnt(3)" ::: "memory");
    __builtin_amdgcn_s_barrier();
    asm volatile("" ::: "memory");

    for (int t = 0; t < NT; ++t) {
        const unsigned short* pA = sA + (t % 3) * APAN;
        const unsigned short* pB = sB + (t % 3) * BPAN;
        short8 b0[4], a0[4];
#pragma unroll
        for (int n = 0; n < 4; ++n)
            b0[n] = *(const short8*)&pB[(kq * 256 + wn * 64 + n * 16 + fr) * 8];
#pragma unroll
        for (int m = 0; m < 4; ++m)
            a0[m] = *(const short8*)&pA[(kq * BM + wm * WROW + m * 16 + fr) * 8];
        if (t + 2 < NT) stageA(t + 2);
        if constexpr (MH == 1) { if (t + 2 < NT) stageB(t + 2); }
        __builtin_amdgcn_s_barrier();
        asm volatile("" ::: "memory");
        __builtin_amdgcn_s_setprio(1);
#pragma unroll
        for (int m = 0; m < 4; ++m)
#pragma unroll
            for (int n = 0; n < 4; ++n)
                acc[m][n] = __builtin_amdgcn_mfma_f32_16x16x32_bf16(a0[m], b0[n], acc[m][n], 0, 0, 0);
        __builtin_amdgcn_s_setprio(0);
        if constexpr (MH == 2) {
            __builtin_amdgcn_s_barrier();
            asm volatile("" ::: "memory");
            short8 a1[4];
#pragma unroll
            for (int m = 0; m < 4; ++m)
                a1[m] = *(const short8*)&pA[(kq * 256 + wm * 128 + 64 + m * 16 + fr) * 8];
            if (t + 2 < NT) stageB(t + 2);
            __builtin_amdgcn_s_barrier();
            asm volatile("" ::: "memory");
            __builtin_amdgcn_s_setprio(1);
#pragma unroll
            for (int m = 0; m < 4; ++m)
#pragma unroll
                for (int n = 0; n < 4; ++n)
                    acc[4 + m][n] = __builtin_amdgcn_mfma_f32_16x16x32_bf16(a1[m], b0[n], acc[4 + m][n], 0, 0, 0);
            __builtin_amdgcn_s_setprio(0);
        }
        if (t + 2 < NT) {
            if constexpr (BM == 256) asm volatile("s_waitcnt vmcnt(4)" ::: "memory");
            else                     asm volatile("s_waitcnt vmcnt(3)" ::: "memory");
        } else if (t + 1 < NT) {
            asm volatile("s_waitcnt vmcnt(0)" ::: "memory");
        }
        __builtin_amdgcn_s_barrier();
        asm volatile("" ::: "memory");
    }

    // C/D layout: col = lane&15, row = (lane>>4)*4 + j
#pragma unroll
    for (int mm = 0; mm < 4 * MH; ++mm) {
        int row0 = bm + wm * WROW + mm * 16 + kq * 4;
#pragma unroll
        for (int j = 0; j < 4; ++j) {
            float* Cr = C + (size_t)(row0 + j) * ldc + bn + wn * 64 + fr;
#pragma unroll
            for (int n = 0; n < 4; ++n) Cr[n * 16] = acc[mm][n][j];
        }
    }
}

// ---------------- causal depthwise conv (D_CONV=4) + SiLU -> bf16 x_conv ----------------
__global__ __launch_bounds__(256) void conv_silu_k(
    const float* __restrict__ xz, const float* __restrict__ conv_w,
    const float* __restrict__ conv_b, unsigned short* __restrict__ x_conv)
{
    int idx = blockIdx.x * 256 + threadIdx.x;   // ROWS * 512 total
    int q = idx & 511;
    int r = idx >> 9;
    int b = r >> 11, t = r & (SEQL - 1);
    int d0 = q << 2;
    float w[4][4];
#pragma unroll
    for (int c = 0; c < 4; ++c) *(float4*)w[c] = *(const float4*)&conv_w[(d0 + c) * 4];
    float4 acc = *(const float4*)&conv_b[d0];
    const float* xp = xz + (size_t)(b * SEQL) * XZ_LD + d0;
#pragma unroll
    for (int k = 0; k < 4; ++k) {
        int t2 = t - 3 + k;
        if (t2 >= 0) {
            float4 v = *(const float4*)(xp + (size_t)t2 * XZ_LD);
            acc.x = fmaf(v.x, w[0][k], acc.x);
            acc.y = fmaf(v.y, w[1][k], acc.y);
            acc.z = fmaf(v.z, w[2][k], acc.z);
            acc.w = fmaf(v.w, w[3][k], acc.w);
        }
    }
    acc.x *= sigmoidf_(acc.x);
    acc.y *= sigmoidf_(acc.y);
    acc.z *= sigmoidf_(acc.z);
    acc.w *= sigmoidf_(acc.w);
    ushort4 hv;
    hv.x = bf16rne(acc.x); hv.y = bf16rne(acc.y);
    hv.z = bf16rne(acc.z); hv.w = bf16rne(acc.w);
    *(ushort4*)&x_conv[(size_t)r * D_INNER + d0] = hv;
}

// ---- x_proj (reads bf16 x_conv) -> A_bar/B_bar/C, [row][s] layout ----
__global__ __launch_bounds__(256) void proj_k(
    const unsigned short* __restrict__ x_conv, const float* __restrict__ W_xproj,
    const float* __restrict__ A_log,
    float* __restrict__ Abar, float* __restrict__ Bbar, float* __restrict__ Cmat)
{
    __shared__ float sdbl[4][33];
    int tid = threadIdx.x;
    int w = tid >> 6, lane = tid & 63;
    int row = blockIdx.x * 4 + w;
    const unsigned short* xrow = x_conv + (size_t)row * D_INNER;
    float xf[32];
#pragma unroll
    for (int it = 0; it < 4; ++it) {
        short8 xv = *(const short8*)&xrow[it * 512 + lane * 8];
#pragma unroll
        for (int j = 0; j < 8; ++j)
            xf[it * 8 + j] = bf2f((unsigned short)xv[j]);
    }

    for (int j = 0; j < 33; ++j) {
        const float* wrow = W_xproj + j * D_INNER;
        float accv = 0.f;
#pragma unroll
        for (int it = 0; it < 4; ++it) {
            float4 w0 = *(const float4*)&wrow[it * 512 + lane * 8];
            float4 w1 = *(const float4*)&wrow[it * 512 + lane * 8 + 4];
            accv = fmaf(xf[it * 8 + 0], w0.x, accv);
            accv = fmaf(xf[it * 8 + 1], w0.y, accv);
            accv = fmaf(xf[it * 8 + 2], w0.z, accv);
            accv = fmaf(xf[it * 8 + 3], w0.w, accv);
            accv = fmaf(xf[it * 8 + 4], w1.x, accv);
            accv = fmaf(xf[it * 8 + 5], w1.y, accv);
            accv = fmaf(xf[it * 8 + 6], w1.z, accv);
            accv = fmaf(xf[it * 8 + 7], w1.w, accv);
        }
#pragma unroll
        for (int off = 32; off; off >>= 1) accv += __shfl_xor(accv, off);
        if (lane == 0) sdbl[w][j] = accv;
    }
    __syncthreads();
    if (tid < 64) {
        int w2 = tid >> 4, s = tid & 15;
        int row2 = blockIdx.x * 4 + w2;
        float draw = sdbl[w2][32];
        float sp = (draw > 20.f) ? draw : log1pf(__expf(draw));
        float dt = fminf(fmaxf(sp, 0.001f), 0.1f);
        float Aa = -__expf(A_log[s]);
        float dtA = fminf(fmaxf(dt * Aa, -20.f), 0.f);
        Abar[row2 * 16 + s] = __expf(dtA);
        float bb = dt * sdbl[w2][s];
        Bbar[row2 * 16 + s] = fminf(fmaxf(bb, -10.f), 10.f);
        Cmat[row2 * 16 + s] = sdbl[w2][16 + s];
    }
}

// ---------------- SSM scan: round-19 structure, x_conv in bf16 ----------------
#define SCH 16
#define TT 16
__global__ __launch_bounds__(256) void scan_k(
    const unsigned short* __restrict__ x_conv, const float* __restrict__ xz,
    unsigned short* __restrict__ yhl,
    const float* __restrict__ Abar, const float* __restrict__ Bbar,
    const float* __restrict__ Cmat, const float* __restrict__ D_param)
{
    __shared__ __align__(16) unsigned short sXa[2][SCH][24];   // bf16 x, 48B rows
    __shared__ float sZp[2][SCH][17];
    __shared__ __align__(16) float sPa[2][16][20];
    __shared__ __align__(16) float sPb[2][16][20];
    __shared__ __align__(16) float sPc[2][16][20];
    __shared__ __align__(16) float sT[SCH][328];

    const int tid = threadIdx.x;
    const int b = blockIdx.y, dbase = blockIdx.x * SCH;
    const int chl = tid >> 4, s = tid & 15;
    const unsigned short* xc = x_conv + (size_t)(b * SEQL) * D_INNER + dbase;
    const float* zp = xz + (size_t)(b * SEQL) * XZ_LD + D_INNER + dbase;
    const int pbase0 = (b * SEQL) * 16;
    const int st = tid >> 4, sc = tid & 15;

    auto stage = [&](int buf, int tc) {
        int t0 = tc * TT;
        sXa[buf][sc][st] = xc[(size_t)(t0 + st) * D_INNER + sc];
        sZp[buf][sc][st] = zp[(size_t)(t0 + st) * XZ_LD + sc];
        int g = pbase0 + t0 * 16 + tid;
        sPa[buf][sc][st] = Abar[g];
        sPb[buf][sc][st] = Bbar[g];
        sPc[buf][sc][st] = Cmat[g];
    };

    stage(0, 0);
    float h = 0.f;
    const float Dp = D_param[dbase + chl];

    for (int tc = 0; tc < SEQL / TT; ++tc) {
        int buf = tc & 1;
        int t0 = tc * TT;
        __syncthreads();
        if (tc + 1 < SEQL / TT) stage(buf ^ 1, tc + 1);

        float p[16];
#pragma unroll
        for (int q = 0; q < 4; ++q) {
            float4 a4 = *(const float4*)&sPa[buf][s][q * 4];
            float4 b4 = *(const float4*)&sPb[buf][s][q * 4];
            float4 c4 = *(const float4*)&sPc[buf][s][q * 4];
            ushort4 xu = *(const ushort4*)&sXa[buf][chl][q * 4];
            float x0 = bf2f(xu.x), x1 = bf2f(xu.y), x2 = bf2f(xu.z), x3 = bf2f(xu.w);
            h = fminf(fmaxf(fmaf(b4.x, x0, a4.x * h), -100.f), 100.f); p[q * 4 + 0] = h * c4.x;
            h = fminf(fmaxf(fmaf(b4.y, x1, a4.y * h), -100.f), 100.f); p[q * 4 + 1] = h * c4.y;
            h = fminf(fmaxf(fmaf(b4.z, x2, a4.z * h), -100.f), 100.f); p[q * 4 + 2] = h * c4.z;
            h = fminf(fmaxf(fmaf(b4.w, x3, a4.w * h), -100.f), 100.f); p[q * 4 + 3] = h * c4.w;
        }

#pragma unroll
        for (int i = 0; i < 16; ++i) sT[chl][i * 20 + s] = p[i];
        float4 r0 = *(const float4*)&sT[chl][s * 20 + 0];
        float4 r1 = *(const float4*)&sT[chl][s * 20 + 4];
        float4 r2 = *(const float4*)&sT[chl][s * 20 + 8];
        float4 r3 = *(const float4*)&sT[chl][s * 20 + 12];
        float ysum = ((r0.x + r1.x + r2.x + r3.x) + (r0.y + r1.y + r2.y + r3.y))
                   + ((r0.z + r1.z + r2.z + r3.z) + (r0.w + r1.w + r2.w + r3.w));

        float z = sZp[buf][chl][s];
        float x = bf2f(sXa[buf][chl][s]);
        float o = fmaf(x, Dp, ysum * (z * sigmoidf_(z)));
        size_t r = (size_t)(b * SEQL + t0 + s);
        yhl[r * 2 * XZ_LD + dbase + chl] = bf16rne(o);
    }
}

extern "C" void kernel_launch(void* const* d_in, const int* in_sizes, int n_in,
                              void* d_out, int out_size, void* d_ws, size_t ws_size,
                              hipStream_t stream) {
    const float* x       = (const float*)d_in[0];
    const float* W_in    = (const float*)d_in[1];
    const float* conv_w  = (const float*)d_in[2];
    const float* conv_b  = (const float*)d_in[3];
    const float* W_xproj = (const float*)d_in[4];
    const float* A_log   = (const float*)d_in[5];
    const float* D_param = (const float*)d_in[6];
    const float* W_out   = (const float*)d_in[7];
    float* out = (float*)d_out;

    // ---- workspace: round-1 footprint (202.9 MB), phase-aliased ----
    char* p = (char*)d_ws;
    char* xzB = p;
    float* xz = (float*)xzB;                 // 134.2 MB; rows: [x_proj | z] fp32
    p += (size_t)ROWS * XZ_LD * 4;
    char* xcB = p;
    unsigned short* x_conv = (unsigned short*)xcB;   // 33.5 MB bf16 (region is 67.1 MB)
    p += (size_t)ROWS * D_INNER * 4;
    float* Abar = (float*)p; p += (size_t)ROWS * 16 * 4;
    float* Bbar = (float*)p; p += (size_t)ROWS * 16 * 4;
    float* Cm   = (float*)p; p += (size_t)ROWS * 16 * 4;

    unsigned short* x1  = (unsigned short*)xcB;      // phase-0 aliases (dead after GEMM1)
    unsigned short* Wi1 = x1 + (size_t)ROWS * D_MODEL;
    unsigned short* Wo1 = x1 + (size_t)ROWS * D_INNER;  // after x_conv, within 67MB region
    unsigned short* yhl = (unsigned short*)xzB;

    constexpr int SM1 = (3 * 256 * 32 + 3 * 256 * 32) * 2;   // 96 KiB
    constexpr int SM2 = (3 * 128 * 32 + 3 * 256 * 32) * 2;   // 72 KiB

    // 0) pack x, W_in -> bf16
    pack1_k<<<ROWS * D_MODEL / 4 / 256, 256, 0, stream>>>(
        (const float4*)x, (ushort4*)x1, ROWS * D_MODEL / 4);
    pack1_k<<<2 * D_INNER * D_MODEL / 4 / 256, 256, 0, stream>>>(
        (const float4*)W_in, (ushort4*)Wi1, 2 * D_INNER * D_MODEL / 4);
    // 1) xz = x @ W_in^T  (M=8192, N=4096, K=1024); BM=256 (r19-proven; r21's BM=128 regressed)
    gemm8p<256><<<dim3(4096 / 256, ROWS / 256), 512, SM1, stream>>>(
        x1, D_MODEL, Wi1, D_MODEL, xz, XZ_LD, D_MODEL);
    // 2) conv + silu -> bf16 x_conv (overwrites phase-0 aliases)
    conv_silu_k<<<ROWS * 512 / 256, 256, 0, stream>>>(xz, conv_w, conv_b, x_conv);
    // 3) x_proj
    proj_k<<<ROWS / 4, 256, 0, stream>>>(x_conv, W_xproj, A_log, Abar, Bbar, Cm);
    // 4) scan -> yh bf16 into xz rows' first half
    scan_k<<<dim3(D_INNER / SCH, NB), 256, 0, stream>>>(
        x_conv, xz, yhl, Abar, Bbar, Cm, D_param);
    // 5) pack W_out -> bf16 (into x_conv region after the bf16 x_conv; x_conv still live
    //    is fine: Wo1 starts at ushort offset ROWS*D_INNER = end of bf16 x_conv)
    pack1_k<<<D_MODEL * D_INNER / 4 / 256, 256, 0, stream>>>(
        (const float4*)W_out, (ushort4*)Wo1, D_MODEL * D_INNER / 4);
    // 6) out = y @ W_out^T  (M=8192, N=1024, K=2048)
    gemm8p<128><<<dim3(1024 / 256, ROWS / 128), 512, SM2, stream>>>(
        yhl, 2 * XZ_LD, Wo1, D_INNER, out, D_MODEL, D_INNER);
}

// Round 23
// 472.543 us; speedup vs baseline: 1.1373x; 1.0057x over previous
//
#include <hip/hip_runtime.h>
#include <cmath>

#define D_MODEL 1024
#define D_STATE 16
#define D_INNER 2048
#define NB 4
#define SEQL 2048
#define ROWS (NB*SEQL)        // 8192
#define XZ_LD (2*D_INNER)     // 4096

typedef __attribute__((ext_vector_type(8))) short short8;
typedef __attribute__((ext_vector_type(4))) float f32x4;

__device__ __forceinline__ float sigmoidf_(float v) { return 1.0f / (1.0f + __expf(-v)); }

__device__ __forceinline__ unsigned short bf16rne(float f) {
    unsigned u = __float_as_uint(f);
    unsigned r = (u + 0x7FFFu + ((u >> 16) & 1u)) >> 16;
    return (unsigned short)r;
}
__device__ __forceinline__ float bf2f(unsigned short u) {
    return __uint_as_float((unsigned)u << 16);
}

// ---------------- fp32 -> bf16 ----------------
__global__ __launch_bounds__(256) void pack1_k(const float4* __restrict__ in,
    ushort4* __restrict__ out, int n4)
{
    int i = blockIdx.x * 256 + threadIdx.x;
    if (i >= n4) return;
    float4 v = in[i];
    ushort4 h;
    h.x = bf16rne(v.x); h.y = bf16rne(v.y); h.z = bf16rne(v.z); h.w = bf16rne(v.w);
    out[i] = h;
}

// ============ 8-phase-style bf16 NT GEMM (round-10 schedule); OB -> bf16 C ============
#define GLDS(gp, lp) __builtin_amdgcn_global_load_lds( \
    (const __attribute__((address_space(1))) void*)(gp), \
    (__attribute__((address_space(3))) void*)(lp), 16, 0, 0)

extern __shared__ __align__(16) unsigned short smem8[];

template<int BM, bool OB>
__global__ __launch_bounds__(512, 2) void gemm8p(
    const unsigned short* __restrict__ A2, int lda,
    const unsigned short* __restrict__ B2, int ldb,
    void* __restrict__ Cv, int ldc, int K)
{
    constexpr int APAN = BM * 32;
    constexpr int BPAN = 256 * 32;
    constexpr int LA   = BM / 128;
    constexpr int MH   = BM / 128;
    constexpr int WROW = (BM == 256) ? 128 : 64;
    unsigned short* sA = smem8;
    unsigned short* sB = smem8 + 3 * APAN;

    const int tid = threadIdx.x;
    const int bm = blockIdx.y * BM, bn = blockIdx.x * 256;
    const int wave = tid >> 6, lane = tid & 63;
    const int wm = wave >> 2, wn = wave & 3;
    const int fr = lane & 15, kq = lane >> 4;
    const int NT = K >> 5;

    size_t offA[LA], offB[2];
#pragma unroll
    for (int i = 0; i < LA; ++i) {
        int c = i * 512 + tid;
        int row = c & (BM - 1), slot = (BM == 256) ? (c >> 8) : (c >> 7);
        offA[i] = (size_t)(bm + row) * lda + slot * 8;
    }
#pragma unroll
    for (int i = 0; i < 2; ++i) {
        int c = i * 512 + tid;
        int row = c & 255, slot = c >> 8;
        offB[i] = (size_t)(bn + row) * ldb + slot * 8;
    }

    auto stageA = [&](int s) {
        int ka = s * 32;
        unsigned short* d = sA + (s % 3) * APAN;
#pragma unroll
        for (int i = 0; i < LA; ++i)
            GLDS(A2 + offA[i] + ka, d + (i * 512 + tid) * 8);
    };
    auto stageB = [&](int s) {
        int kb = s * 32;
        unsigned short* d = sB + (s % 3) * BPAN;
#pragma unroll
        for (int i = 0; i < 2; ++i)
            GLDS(B2 + offB[i] + kb, d + (i * 512 + tid) * 8);
    };

    f32x4 acc[4 * MH][4];
#pragma unroll
    for (int m = 0; m < 4 * MH; ++m)
#pragma unroll
        for (int n = 0; n < 4; ++n) acc[m][n] = (f32x4){0.f, 0.f, 0.f, 0.f};

    stageA(0); stageB(0); stageA(1); stageB(1);
    if constexpr (BM == 256) asm volatile("s_waitcnt vmcnt(4)" ::: "memory");
    else                     asm volatile("s_waitcnt vmcnt(3)" ::: "memory");
    __builtin_amdgcn_s_barrier();
    asm volatile("" ::: "memory");

    for (int t = 0; t < NT; ++t) {
        const unsigned short* pA = sA + (t % 3) * APAN;
        const unsigned short* pB = sB + (t % 3) * BPAN;
        short8 b0[4], a0[4];
#pragma unroll
        for (int n = 0; n < 4; ++n)
            b0[n] = *(const short8*)&pB[(kq * 256 + wn * 64 + n * 16 + fr) * 8];
#pragma unroll
        for (int m = 0; m < 4; ++m)
            a0[m] = *(const short8*)&pA[(kq * BM + wm * WROW + m * 16 + fr) * 8];
        if (t + 2 < NT) stageA(t + 2);
        if constexpr (MH == 1) { if (t + 2 < NT) stageB(t + 2); }
        __builtin_amdgcn_s_barrier();
        asm volatile("" ::: "memory");
        __builtin_amdgcn_s_setprio(1);
#pragma unroll
        for (int m = 0; m < 4; ++m)
#pragma unroll
            for (int n = 0; n < 4; ++n)
                acc[m][n] = __builtin_amdgcn_mfma_f32_16x16x32_bf16(a0[m], b0[n], acc[m][n], 0, 0, 0);
        __builtin_amdgcn_s_setprio(0);
        if constexpr (MH == 2) {
            __builtin_amdgcn_s_barrier();
            asm volatile("" ::: "memory");
            short8 a1[4];
#pragma unroll
            for (int m = 0; m < 4; ++m)
                a1[m] = *(const short8*)&pA[(kq * 256 + wm * 128 + 64 + m * 16 + fr) * 8];
            if (t + 2 < NT) stageB(t + 2);
            __builtin_amdgcn_s_barrier();
            asm volatile("" ::: "memory");
            __builtin_amdgcn_s_setprio(1);
#pragma unroll
            for (int m = 0; m < 4; ++m)
#pragma unroll
                for (int n = 0; n < 4; ++n)
                    acc[4 + m][n] = __builtin_amdgcn_mfma_f32_16x16x32_bf16(a1[m], b0[n], acc[4 + m][n], 0, 0, 0);
            __builtin_amdgcn_s_setprio(0);
        }
        if (t + 2 < NT) {
            if constexpr (BM == 256) asm volatile("s_waitcnt vmcnt(4)" ::: "memory");
            else                     asm volatile("s_waitcnt vmcnt(3)" ::: "memory");
        } else if (t + 1 < NT) {
            asm volatile("s_waitcnt vmcnt(0)" ::: "memory");
        }
        __builtin_amdgcn_s_barrier();
        asm volatile("" ::: "memory");
    }

    // C/D layout: col = lane&15, row = (lane>>4)*4 + j
#pragma unroll
    for (int mm = 0; mm < 4 * MH; ++mm) {
        int row0 = bm + wm * WROW + mm * 16 + kq * 4;
#pragma unroll
        for (int j = 0; j < 4; ++j) {
            if constexpr (OB) {
                unsigned short* Cr = (unsigned short*)Cv + (size_t)(row0 + j) * ldc + bn + wn * 64 + fr;
#pragma unroll
                for (int n = 0; n < 4; ++n) Cr[n * 16] = bf16rne(acc[mm][n][j]);
            } else {
                float* Cr = (float*)Cv + (size_t)(row0 + j) * ldc + bn + wn * 64 + fr;
#pragma unroll
                for (int n = 0; n < 4; ++n) Cr[n * 16] = acc[mm][n][j];
            }
        }
    }
}

// ---------------- causal depthwise conv (D_CONV=4) + SiLU, bf16 in/out ----------------
__global__ __launch_bounds__(256) void conv_silu_k(
    const unsigned short* __restrict__ xz, const float* __restrict__ conv_w,
    const float* __restrict__ conv_b, unsigned short* __restrict__ x_conv)
{
    int idx = blockIdx.x * 256 + threadIdx.x;   // ROWS * 512 total
    int q = idx & 511;
    int r = idx >> 9;
    int b = r >> 11, t = r & (SEQL - 1);
    int d0 = q << 2;
    float w[4][4];
#pragma unroll
    for (int c = 0; c < 4; ++c) *(float4*)w[c] = *(const float4*)&conv_w[(d0 + c) * 4];
    float4 acc = *(const float4*)&conv_b[d0];
    const unsigned short* xp = xz + (size_t)(b * SEQL) * XZ_LD + d0;
#pragma unroll
    for (int k = 0; k < 4; ++k) {
        int t2 = t - 3 + k;
        if (t2 >= 0) {
            ushort4 v = *(const ushort4*)(xp + (size_t)t2 * XZ_LD);
            acc.x = fmaf(bf2f(v.x), w[0][k], acc.x);
            acc.y = fmaf(bf2f(v.y), w[1][k], acc.y);
            acc.z = fmaf(bf2f(v.z), w[2][k], acc.z);
            acc.w = fmaf(bf2f(v.w), w[3][k], acc.w);
        }
    }
    acc.x *= sigmoidf_(acc.x);
    acc.y *= sigmoidf_(acc.y);
    acc.z *= sigmoidf_(acc.z);
    acc.w *= sigmoidf_(acc.w);
    ushort4 hv;
    hv.x = bf16rne(acc.x); hv.y = bf16rne(acc.y);
    hv.z = bf16rne(acc.z); hv.w = bf16rne(acc.w);
    *(ushort4*)&x_conv[(size_t)r * D_INNER + d0] = hv;
}

// ---- x_proj (bf16 x_conv) -> A_bar fp32, B_bar/C bf16, [row][s] layout ----
__global__ __launch_bounds__(256) void proj_k(
    const unsigned short* __restrict__ x_conv, const float* __restrict__ W_xproj,
    const float* __restrict__ A_log,
    float* __restrict__ Abar, unsigned short* __restrict__ Bbar,
    unsigned short* __restrict__ Cmat)
{
    __shared__ float sdbl[4][33];
    int tid = threadIdx.x;
    int w = tid >> 6, lane = tid & 63;
    int row = blockIdx.x * 4 + w;
    const unsigned short* xrow = x_conv + (size_t)row * D_INNER;
    float xf[32];
#pragma unroll
    for (int it = 0; it < 4; ++it) {
        short8 xv = *(const short8*)&xrow[it * 512 + lane * 8];
#pragma unroll
        for (int j = 0; j < 8; ++j)
            xf[it * 8 + j] = bf2f((unsigned short)xv[j]);
    }

    for (int j = 0; j < 33; ++j) {
        const float* wrow = W_xproj + j * D_INNER;
        float accv = 0.f;
#pragma unroll
        for (int it = 0; it < 4; ++it) {
            float4 w0 = *(const float4*)&wrow[it * 512 + lane * 8];
            float4 w1 = *(const float4*)&wrow[it * 512 + lane * 8 + 4];
            accv = fmaf(xf[it * 8 + 0], w0.x, accv);
            accv = fmaf(xf[it * 8 + 1], w0.y, accv);
            accv = fmaf(xf[it * 8 + 2], w0.z, accv);
            accv = fmaf(xf[it * 8 + 3], w0.w, accv);
            accv = fmaf(xf[it * 8 + 4], w1.x, accv);
            accv = fmaf(xf[it * 8 + 5], w1.y, accv);
            accv = fmaf(xf[it * 8 + 6], w1.z, accv);
            accv = fmaf(xf[it * 8 + 7], w1.w, accv);
        }
#pragma unroll
        for (int off = 32; off; off >>= 1) accv += __shfl_xor(accv, off);
        if (lane == 0) sdbl[w][j] = accv;
    }
    __syncthreads();
    if (tid < 64) {
        int w2 = tid >> 4, s = tid & 15;
        int row2 = blockIdx.x * 4 + w2;
        float draw = sdbl[w2][32];
        float sp = (draw > 20.f) ? draw : log1pf(__expf(draw));
        float dt = fminf(fmaxf(sp, 0.001f), 0.1f);
        float Aa = -__expf(A_log[s]);
        float dtA = fminf(fmaxf(dt * Aa, -20.f), 0.f);
        Abar[row2 * 16 + s] = __expf(dtA);          // fp32: error compounds over horizon
        float bb = dt * sdbl[w2][s];
        Bbar[row2 * 16 + s] = bf16rne(fminf(fmaxf(bb, -10.f), 10.f));   // linear: bf16 ok
        Cmat[row2 * 16 + s] = bf16rne(sdbl[w2][16 + s]);
    }
}

// ---------------- SSM scan: r19 structure; B/C/x bf16 in LDS, A fp32 ----------------
#define SCH 16
#define TT 16
__global__ __launch_bounds__(256) void scan_k(
    const unsigned short* __restrict__ x_conv, const unsigned short* __restrict__ xz,
    unsigned short* __restrict__ yhl,
    const float* __restrict__ Abar, const unsigned short* __restrict__ Bbar,
    const unsigned short* __restrict__ Cmat, const float* __restrict__ D_param)
{
    __shared__ __align__(16) unsigned short sXa[2][SCH][24];   // bf16 x
    __shared__ float sZp[2][SCH][17];                          // z (converted at stage)
    __shared__ __align__(16) float sPa[2][16][20];             // A fp32
    __shared__ __align__(16) unsigned short sPb[2][16][20];    // B bf16
    __shared__ __align__(16) unsigned short sPc[2][16][20];    // C bf16
    __shared__ __align__(16) float sT[SCH][328];

    const int tid = threadIdx.x;
    const int b = blockIdx.y, dbase = blockIdx.x * SCH;
    const int chl = tid >> 4, s = tid & 15;
    const unsigned short* xc = x_conv + (size_t)(b * SEQL) * D_INNER + dbase;
    const unsigned short* zp = xz + (size_t)(b * SEQL) * XZ_LD + D_INNER + dbase;
    const int pbase0 = (b * SEQL) * 16;
    const int st = tid >> 4, sc = tid & 15;

    auto stage = [&](int buf, int tc) {
        int t0 = tc * TT;
        sXa[buf][sc][st] = xc[(size_t)(t0 + st) * D_INNER + sc];
        sZp[buf][sc][st] = bf2f(zp[(size_t)(t0 + st) * XZ_LD + sc]);
        int g = pbase0 + t0 * 16 + tid;
        sPa[buf][sc][st] = Abar[g];
        sPb[buf][sc][st] = Bbar[g];
        sPc[buf][sc][st] = Cmat[g];
    };

    stage(0, 0);
    float h = 0.f;
    const float Dp = D_param[dbase + chl];

    for (int tc = 0; tc < SEQL / TT; ++tc) {
        int buf = tc & 1;
        int t0 = tc * TT;
        __syncthreads();
        if (tc + 1 < SEQL / TT) stage(buf ^ 1, tc + 1);

        float p[16];
#pragma unroll
        for (int q = 0; q < 4; ++q) {
            float4 a4 = *(const float4*)&sPa[buf][s][q * 4];
            ushort4 bu = *(const ushort4*)&sPb[buf][s][q * 4];
            ushort4 cu = *(const ushort4*)&sPc[buf][s][q * 4];
            ushort4 xu = *(const ushort4*)&sXa[buf][chl][q * 4];
            float b0 = bf2f(bu.x), b1 = bf2f(bu.y), b2 = bf2f(bu.z), b3 = bf2f(bu.w);
            float c0 = bf2f(cu.x), c1 = bf2f(cu.y), c2 = bf2f(cu.z), c3 = bf2f(cu.w);
            float x0 = bf2f(xu.x), x1 = bf2f(xu.y), x2 = bf2f(xu.z), x3 = bf2f(xu.w);
            h = fminf(fmaxf(fmaf(b0, x0, a4.x * h), -100.f), 100.f); p[q * 4 + 0] = h * c0;
            h = fminf(fmaxf(fmaf(b1, x1, a4.y * h), -100.f), 100.f); p[q * 4 + 1] = h * c1;
            h = fminf(fmaxf(fmaf(b2, x2, a4.z * h), -100.f), 100.f); p[q * 4 + 2] = h * c2;
            h = fminf(fmaxf(fmaf(b3, x3, a4.w * h), -100.f), 100.f); p[q * 4 + 3] = h * c3;
        }

#pragma unroll
        for (int i = 0; i < 16; ++i) sT[chl][i * 20 + s] = p[i];
        float4 r0 = *(const float4*)&sT[chl][s * 20 + 0];
        float4 r1 = *(const float4*)&sT[chl][s * 20 + 4];
        float4 r2 = *(const float4*)&sT[chl][s * 20 + 8];
        float4 r3 = *(const float4*)&sT[chl][s * 20 + 12];
        float ysum = ((r0.x + r1.x + r2.x + r3.x) + (r0.y + r1.y + r2.y + r3.y))
                   + ((r0.z + r1.z + r2.z + r3.z) + (r0.w + r1.w + r2.w + r3.w));

        float z = sZp[buf][chl][s];
        float x = bf2f(sXa[buf][chl][s]);
        float o = fmaf(x, Dp, ysum * (z * sigmoidf_(z)));
        size_t r = (size_t)(b * SEQL + t0 + s);
        yhl[r * XZ_LD + dbase + chl] = bf16rne(o);
    }
}

extern "C" void kernel_launch(void* const* d_in, const int* in_sizes, int n_in,
                              void* d_out, int out_size, void* d_ws, size_t ws_size,
                              hipStream_t stream) {
    const float* x       = (const float*)d_in[0];
    const float* W_in    = (const float*)d_in[1];
    const float* conv_w  = (const float*)d_in[2];
    const float* conv_b  = (const float*)d_in[3];
    const float* W_xproj = (const float*)d_in[4];
    const float* A_log   = (const float*)d_in[5];
    const float* D_param = (const float*)d_in[6];
    const float* W_out   = (const float*)d_in[7];
    float* out = (float*)d_out;

    // ---- workspace: round-1 footprint (202.9 MB), phase-aliased ----
    char* p = (char*)d_ws;
    char* xzB = p;
    unsigned short* xz = (unsigned short*)xzB;   // xz now bf16: ROWS x XZ_LD ushorts (67 MB)
    p += (size_t)ROWS * XZ_LD * 4;               // region still reserved at fp32 size
    char* xcB = p;
    unsigned short* x_conv = (unsigned short*)xcB;   // 33.5 MB bf16
    p += (size_t)ROWS * D_INNER * 4;
    float*          Abar = (float*)p;          p += (size_t)ROWS * 16 * 4;
    unsigned short* Bbar = (unsigned short*)p; p += (size_t)ROWS * 16 * 4;
    unsigned short* Cm   = (unsigned short*)p; p += (size_t)ROWS * 16 * 4;

    unsigned short* x1  = (unsigned short*)xcB;      // phase-0 aliases (dead after GEMM1)
    unsigned short* Wi1 = x1 + (size_t)ROWS * D_MODEL;
    unsigned short* Wo1 = x1 + (size_t)ROWS * D_INNER;  // after bf16 x_conv
    unsigned short* yhl = (unsigned short*)xzB;          // yh in x_proj half, pitch XZ_LD

    constexpr int SM1 = (3 * 256 * 32 + 3 * 256 * 32) * 2;   // 96 KiB
    constexpr int SM2 = (3 * 128 * 32 + 3 * 256 * 32) * 2;   // 72 KiB

    // 0) pack x, W_in -> bf16
    pack1_k<<<ROWS * D_MODEL / 4 / 256, 256, 0, stream>>>(
        (const float4*)x, (ushort4*)x1, ROWS * D_MODEL / 4);
    pack1_k<<<2 * D_INNER * D_MODEL / 4 / 256, 256, 0, stream>>>(
        (const float4*)W_in, (ushort4*)Wi1, 2 * D_INNER * D_MODEL / 4);
    // 1) xz = x @ W_in^T, bf16 output (write 134 -> 67 MB)
    gemm8p<256, true><<<dim3(4096 / 256, ROWS / 256), 512, SM1, stream>>>(
        x1, D_MODEL, Wi1, D_MODEL, xz, XZ_LD, D_MODEL);
    // 2) conv + silu (bf16 in/out)
    conv_silu_k<<<ROWS * 512 / 256, 256, 0, stream>>>(xz, conv_w, conv_b, x_conv);
    // 3) x_proj -> A fp32, B/C bf16
    proj_k<<<ROWS / 4, 256, 0, stream>>>(x_conv, W_xproj, A_log, Abar, Bbar, Cm);
    // 4) scan -> yh bf16 into xz rows' first half (pitch XZ_LD)
    scan_k<<<dim3(D_INNER / SCH, NB), 256, 0, stream>>>(
        x_conv, xz, yhl, Abar, Bbar, Cm, D_param);
    // 5) pack W_out -> bf16
    pack1_k<<<D_MODEL * D_INNER / 4 / 256, 256, 0, stream>>>(
        (const float4*)W_out, (ushort4*)Wo1, D_MODEL * D_INNER / 4);
    // 6) out = y @ W_out^T (fp32 output)
    gemm8p<128, false><<<dim3(1024 / 256, ROWS / 128), 512, SM2, stream>>>(
        yhl, XZ_LD, Wo1, D_INNER, out, D_MODEL, D_INNER);
}

// Round 24
// 464.961 us; speedup vs baseline: 1.1558x; 1.0163x over previous
//
#include <hip/hip_runtime.h>
#include <cmath>

#define D_MODEL 1024
#define D_STATE 16
#define D_INNER 2048
#define NB 4
#define SEQL 2048
#define ROWS (NB*SEQL)        // 8192
#define XZ_LD (2*D_INNER)     // 4096

typedef __attribute__((ext_vector_type(8))) short short8;
typedef __attribute__((ext_vector_type(4))) float f32x4;

__device__ __forceinline__ float sigmoidf_(float v) { return 1.0f / (1.0f + __expf(-v)); }

__device__ __forceinline__ unsigned short bf16rne(float f) {
    unsigned u = __float_as_uint(f);
    unsigned r = (u + 0x7FFFu + ((u >> 16) & 1u)) >> 16;
    return (unsigned short)r;
}
__device__ __forceinline__ float bf2f(unsigned short u) {
    return __uint_as_float((unsigned)u << 16);
}

// ---------------- fp32 -> bf16 ----------------
__global__ __launch_bounds__(256) void pack1_k(const float4* __restrict__ in,
    ushort4* __restrict__ out, int n4)
{
    int i = blockIdx.x * 256 + threadIdx.x;
    if (i >= n4) return;
    float4 v = in[i];
    ushort4 h;
    h.x = bf16rne(v.x); h.y = bf16rne(v.y); h.z = bf16rne(v.z); h.w = bf16rne(v.w);
    out[i] = h;
}

// ============ 8-phase-style bf16 NT GEMM (round-10 schedule); OB -> bf16 C ============
#define GLDS(gp, lp) __builtin_amdgcn_global_load_lds( \
    (const __attribute__((address_space(1))) void*)(gp), \
    (__attribute__((address_space(3))) void*)(lp), 16, 0, 0)

extern __shared__ __align__(16) unsigned short smem8[];

template<int BM, bool OB>
__global__ __launch_bounds__(512, 2) void gemm8p(
    const unsigned short* __restrict__ A2, int lda,
    const unsigned short* __restrict__ B2, int ldb,
    void* __restrict__ Cv, int ldc, int K)
{
    constexpr int APAN = BM * 32;
    constexpr int BPAN = 256 * 32;
    constexpr int LA   = BM / 128;
    constexpr int MH   = BM / 128;
    constexpr int WROW = (BM == 256) ? 128 : 64;
    unsigned short* sA = smem8;
    unsigned short* sB = smem8 + 3 * APAN;

    const int tid = threadIdx.x;
    const int bm = blockIdx.y * BM, bn = blockIdx.x * 256;
    const int wave = tid >> 6, lane = tid & 63;
    const int wm = wave >> 2, wn = wave & 3;
    const int fr = lane & 15, kq = lane >> 4;
    const int NT = K >> 5;

    size_t offA[LA], offB[2];
#pragma unroll
    for (int i = 0; i < LA; ++i) {
        int c = i * 512 + tid;
        int row = c & (BM - 1), slot = (BM == 256) ? (c >> 8) : (c >> 7);
        offA[i] = (size_t)(bm + row) * lda + slot * 8;
    }
#pragma unroll
    for (int i = 0; i < 2; ++i) {
        int c = i * 512 + tid;
        int row = c & 255, slot = c >> 8;
        offB[i] = (size_t)(bn + row) * ldb + slot * 8;
    }

    auto stageA = [&](int s) {
        int ka = s * 32;
        unsigned short* d = sA + (s % 3) * APAN;
#pragma unroll
        for (int i = 0; i < LA; ++i)
            GLDS(A2 + offA[i] + ka, d + (i * 512 + tid) * 8);
    };
    auto stageB = [&](int s) {
        int kb = s * 32;
        unsigned short* d = sB + (s % 3) * BPAN;
#pragma unroll
        for (int i = 0; i < 2; ++i)
            GLDS(B2 + offB[i] + kb, d + (i * 512 + tid) * 8);
    };

    f32x4 acc[4 * MH][4];
#pragma unroll
    for (int m = 0; m < 4 * MH; ++m)
#pragma unroll
        for (int n = 0; n < 4; ++n) acc[m][n] = (f32x4){0.f, 0.f, 0.f, 0.f};

    stageA(0); stageB(0); stageA(1); stageB(1);
    if constexpr (BM == 256) asm volatile("s_waitcnt vmcnt(4)" ::: "memory");
    else                     asm volatile("s_waitcnt vmcnt(3)" ::: "memory");
    __builtin_amdgcn_s_barrier();
    asm volatile("" ::: "memory");

    for (int t = 0; t < NT; ++t) {
        const unsigned short* pA = sA + (t % 3) * APAN;
        const unsigned short* pB = sB + (t % 3) * BPAN;
        short8 b0[4], a0[4];
#pragma unroll
        for (int n = 0; n < 4; ++n)
            b0[n] = *(const short8*)&pB[(kq * 256 + wn * 64 + n * 16 + fr) * 8];
#pragma unroll
        for (int m = 0; m < 4; ++m)
            a0[m] = *(const short8*)&pA[(kq * BM + wm * WROW + m * 16 + fr) * 8];
        if (t + 2 < NT) stageA(t + 2);
        if constexpr (MH == 1) { if (t + 2 < NT) stageB(t + 2); }
        __builtin_amdgcn_s_barrier();
        asm volatile("" ::: "memory");
        __builtin_amdgcn_s_setprio(1);
#pragma unroll
        for (int m = 0; m < 4; ++m)
#pragma unroll
            for (int n = 0; n < 4; ++n)
                acc[m][n] = __builtin_amdgcn_mfma_f32_16x16x32_bf16(a0[m], b0[n], acc[m][n], 0, 0, 0);
        __builtin_amdgcn_s_setprio(0);
        if constexpr (MH == 2) {
            __builtin_amdgcn_s_barrier();
            asm volatile("" ::: "memory");
            short8 a1[4];
#pragma unroll
            for (int m = 0; m < 4; ++m)
                a1[m] = *(const short8*)&pA[(kq * 256 + wm * 128 + 64 + m * 16 + fr) * 8];
            if (t + 2 < NT) stageB(t + 2);
            __builtin_amdgcn_s_barrier();
            asm volatile("" ::: "memory");
            __builtin_amdgcn_s_setprio(1);
#pragma unroll
            for (int m = 0; m < 4; ++m)
#pragma unroll
                for (int n = 0; n < 4; ++n)
                    acc[4 + m][n] = __builtin_amdgcn_mfma_f32_16x16x32_bf16(a1[m], b0[n], acc[4 + m][n], 0, 0, 0);
            __builtin_amdgcn_s_setprio(0);
        }
        if (t + 2 < NT) {
            if constexpr (BM == 256) asm volatile("s_waitcnt vmcnt(4)" ::: "memory");
            else                     asm volatile("s_waitcnt vmcnt(3)" ::: "memory");
        } else if (t + 1 < NT) {
            asm volatile("s_waitcnt vmcnt(0)" ::: "memory");
        }
        __builtin_amdgcn_s_barrier();
        asm volatile("" ::: "memory");
    }

    // C/D layout: col = lane&15, row = (lane>>4)*4 + j
#pragma unroll
    for (int mm = 0; mm < 4 * MH; ++mm) {
        int row0 = bm + wm * WROW + mm * 16 + kq * 4;
#pragma unroll
        for (int j = 0; j < 4; ++j) {
            if constexpr (OB) {
                unsigned short* Cr = (unsigned short*)Cv + (size_t)(row0 + j) * ldc + bn + wn * 64 + fr;
#pragma unroll
                for (int n = 0; n < 4; ++n) Cr[n * 16] = bf16rne(acc[mm][n][j]);
            } else {
                float* Cr = (float*)Cv + (size_t)(row0 + j) * ldc + bn + wn * 64 + fr;
#pragma unroll
                for (int n = 0; n < 4; ++n) Cr[n * 16] = acc[mm][n][j];
            }
        }
    }
}

// ---------------- causal depthwise conv (D_CONV=4) + SiLU, bf16 in/out ----------------
__global__ __launch_bounds__(256) void conv_silu_k(
    const unsigned short* __restrict__ xz, const float* __restrict__ conv_w,
    const float* __restrict__ conv_b, unsigned short* __restrict__ x_conv)
{
    int idx = blockIdx.x * 256 + threadIdx.x;   // ROWS * 512 total
    int q = idx & 511;
    int r = idx >> 9;
    int b = r >> 11, t = r & (SEQL - 1);
    int d0 = q << 2;
    float w[4][4];
#pragma unroll
    for (int c = 0; c < 4; ++c) *(float4*)w[c] = *(const float4*)&conv_w[(d0 + c) * 4];
    float4 acc = *(const float4*)&conv_b[d0];
    const unsigned short* xp = xz + (size_t)(b * SEQL) * XZ_LD + d0;
#pragma unroll
    for (int k = 0; k < 4; ++k) {
        int t2 = t - 3 + k;
        if (t2 >= 0) {
            ushort4 v = *(const ushort4*)(xp + (size_t)t2 * XZ_LD);
            acc.x = fmaf(bf2f(v.x), w[0][k], acc.x);
            acc.y = fmaf(bf2f(v.y), w[1][k], acc.y);
            acc.z = fmaf(bf2f(v.z), w[2][k], acc.z);
            acc.w = fmaf(bf2f(v.w), w[3][k], acc.w);
        }
    }
    acc.x *= sigmoidf_(acc.x);
    acc.y *= sigmoidf_(acc.y);
    acc.z *= sigmoidf_(acc.z);
    acc.w *= sigmoidf_(acc.w);
    ushort4 hv;
    hv.x = bf16rne(acc.x); hv.y = bf16rne(acc.y);
    hv.z = bf16rne(acc.z); hv.w = bf16rne(acc.w);
    *(ushort4*)&x_conv[(size_t)r * D_INNER + d0] = hv;
}

// ---- x_proj (bf16 x_conv) -> A_bar/B_bar/C fp32, [row][s] layout ----
__global__ __launch_bounds__(256) void proj_k(
    const unsigned short* __restrict__ x_conv, const float* __restrict__ W_xproj,
    const float* __restrict__ A_log,
    float* __restrict__ Abar, float* __restrict__ Bbar, float* __restrict__ Cmat)
{
    __shared__ float sdbl[4][33];
    int tid = threadIdx.x;
    int w = tid >> 6, lane = tid & 63;
    int row = blockIdx.x * 4 + w;
    const unsigned short* xrow = x_conv + (size_t)row * D_INNER;
    float xf[32];
#pragma unroll
    for (int it = 0; it < 4; ++it) {
        short8 xv = *(const short8*)&xrow[it * 512 + lane * 8];
#pragma unroll
        for (int j = 0; j < 8; ++j)
            xf[it * 8 + j] = bf2f((unsigned short)xv[j]);
    }

    for (int j = 0; j < 33; ++j) {
        const float* wrow = W_xproj + j * D_INNER;
        float accv = 0.f;
#pragma unroll
        for (int it = 0; it < 4; ++it) {
            float4 w0 = *(const float4*)&wrow[it * 512 + lane * 8];
            float4 w1 = *(const float4*)&wrow[it * 512 + lane * 8 + 4];
            accv = fmaf(xf[it * 8 + 0], w0.x, accv);
            accv = fmaf(xf[it * 8 + 1], w0.y, accv);
            accv = fmaf(xf[it * 8 + 2], w0.z, accv);
            accv = fmaf(xf[it * 8 + 3], w0.w, accv);
            accv = fmaf(xf[it * 8 + 4], w1.x, accv);
            accv = fmaf(xf[it * 8 + 5], w1.y, accv);
            accv = fmaf(xf[it * 8 + 6], w1.z, accv);
            accv = fmaf(xf[it * 8 + 7], w1.w, accv);
        }
#pragma unroll
        for (int off = 32; off; off >>= 1) accv += __shfl_xor(accv, off);
        if (lane == 0) sdbl[w][j] = accv;
    }
    __syncthreads();
    if (tid < 64) {
        int w2 = tid >> 4, s = tid & 15;
        int row2 = blockIdx.x * 4 + w2;
        float draw = sdbl[w2][32];
        float sp = (draw > 20.f) ? draw : log1pf(__expf(draw));
        float dt = fminf(fmaxf(sp, 0.001f), 0.1f);
        float Aa = -__expf(A_log[s]);
        float dtA = fminf(fmaxf(dt * Aa, -20.f), 0.f);
        Abar[row2 * 16 + s] = __expf(dtA);
        float bb = dt * sdbl[w2][s];
        Bbar[row2 * 16 + s] = fminf(fmaxf(bb, -10.f), 10.f);
        Cmat[row2 * 16 + s] = sdbl[w2][16 + s];
    }
}

// ---------------- SSM scan: r19 structure; x/z bf16 HBM, A/B/C fp32 params ----------------
#define SCH 16
#define TT 16
__global__ __launch_bounds__(256) void scan_k(
    const unsigned short* __restrict__ x_conv, const unsigned short* __restrict__ xz,
    unsigned short* __restrict__ yhl,
    const float* __restrict__ Abar, const float* __restrict__ Bbar,
    const float* __restrict__ Cmat, const float* __restrict__ D_param)
{
    __shared__ __align__(16) unsigned short sXa[2][SCH][24];   // bf16 x
    __shared__ float sZp[2][SCH][17];                          // z fp32 (converted at stage)
    __shared__ __align__(16) float sPa[2][16][20];             // A fp32
    __shared__ __align__(16) float sPb[2][16][20];             // B fp32 (r22 path: no converts)
    __shared__ __align__(16) float sPc[2][16][20];             // C fp32
    __shared__ __align__(16) float sT[SCH][328];

    const int tid = threadIdx.x;
    const int b = blockIdx.y, dbase = blockIdx.x * SCH;
    const int chl = tid >> 4, s = tid & 15;
    const unsigned short* xc = x_conv + (size_t)(b * SEQL) * D_INNER + dbase;
    const unsigned short* zp = xz + (size_t)(b * SEQL) * XZ_LD + D_INNER + dbase;
    const int pbase0 = (b * SEQL) * 16;
    const int st = tid >> 4, sc = tid & 15;

    auto stage = [&](int buf, int tc) {
        int t0 = tc * TT;
        sXa[buf][sc][st] = xc[(size_t)(t0 + st) * D_INNER + sc];
        sZp[buf][sc][st] = bf2f(zp[(size_t)(t0 + st) * XZ_LD + sc]);
        int g = pbase0 + t0 * 16 + tid;
        sPa[buf][sc][st] = Abar[g];
        sPb[buf][sc][st] = Bbar[g];
        sPc[buf][sc][st] = Cmat[g];
    };

    stage(0, 0);
    float h = 0.f;
    const float Dp = D_param[dbase + chl];

    for (int tc = 0; tc < SEQL / TT; ++tc) {
        int buf = tc & 1;
        int t0 = tc * TT;
        __syncthreads();
        if (tc + 1 < SEQL / TT) stage(buf ^ 1, tc + 1);

        float p[16];
#pragma unroll
        for (int q = 0; q < 4; ++q) {
            float4 a4 = *(const float4*)&sPa[buf][s][q * 4];
            float4 b4 = *(const float4*)&sPb[buf][s][q * 4];
            float4 c4 = *(const float4*)&sPc[buf][s][q * 4];
            ushort4 xu = *(const ushort4*)&sXa[buf][chl][q * 4];
            float x0 = bf2f(xu.x), x1 = bf2f(xu.y), x2 = bf2f(xu.z), x3 = bf2f(xu.w);
            h = fminf(fmaxf(fmaf(b4.x, x0, a4.x * h), -100.f), 100.f); p[q * 4 + 0] = h * c4.x;
            h = fminf(fmaxf(fmaf(b4.y, x1, a4.y * h), -100.f), 100.f); p[q * 4 + 1] = h * c4.y;
            h = fminf(fmaxf(fmaf(b4.z, x2, a4.z * h), -100.f), 100.f); p[q * 4 + 2] = h * c4.z;
            h = fminf(fmaxf(fmaf(b4.w, x3, a4.w * h), -100.f), 100.f); p[q * 4 + 3] = h * c4.w;
        }

#pragma unroll
        for (int i = 0; i < 16; ++i) sT[chl][i * 20 + s] = p[i];
        float4 r0 = *(const float4*)&sT[chl][s * 20 + 0];
        float4 r1 = *(const float4*)&sT[chl][s * 20 + 4];
        float4 r2 = *(const float4*)&sT[chl][s * 20 + 8];
        float4 r3 = *(const float4*)&sT[chl][s * 20 + 12];
        float ysum = ((r0.x + r1.x + r2.x + r3.x) + (r0.y + r1.y + r2.y + r3.y))
                   + ((r0.z + r1.z + r2.z + r3.z) + (r0.w + r1.w + r2.w + r3.w));

        float z = sZp[buf][chl][s];
        float x = bf2f(sXa[buf][chl][s]);
        float o = fmaf(x, Dp, ysum * (z * sigmoidf_(z)));
        size_t r = (size_t)(b * SEQL + t0 + s);
        yhl[r * XZ_LD + dbase + chl] = bf16rne(o);
    }
}

extern "C" void kernel_launch(void* const* d_in, const int* in_sizes, int n_in,
                              void* d_out, int out_size, void* d_ws, size_t ws_size,
                              hipStream_t stream) {
    const float* x       = (const float*)d_in[0];
    const float* W_in    = (const float*)d_in[1];
    const float* conv_w  = (const float*)d_in[2];
    const float* conv_b  = (const float*)d_in[3];
    const float* W_xproj = (const float*)d_in[4];
    const float* A_log   = (const float*)d_in[5];
    const float* D_param = (const float*)d_in[6];
    const float* W_out   = (const float*)d_in[7];
    float* out = (float*)d_out;

    // ---- workspace: round-1 footprint (202.9 MB), phase-aliased ----
    char* p = (char*)d_ws;
    char* xzB = p;
    unsigned short* xz = (unsigned short*)xzB;   // bf16 xz: ROWS x XZ_LD ushorts (67 MB)
    p += (size_t)ROWS * XZ_LD * 4;               // region reserved at fp32 size
    char* xcB = p;
    unsigned short* x_conv = (unsigned short*)xcB;   // 33.5 MB bf16
    p += (size_t)ROWS * D_INNER * 4;
    float* Abar = (float*)p; p += (size_t)ROWS * 16 * 4;
    float* Bbar = (float*)p; p += (size_t)ROWS * 16 * 4;
    float* Cm   = (float*)p; p += (size_t)ROWS * 16 * 4;

    unsigned short* x1  = (unsigned short*)xcB;      // phase-0 aliases (dead after GEMM1)
    unsigned short* Wi1 = x1 + (size_t)ROWS * D_MODEL;
    unsigned short* Wo1 = x1 + (size_t)ROWS * D_INNER;  // after bf16 x_conv
    unsigned short* yhl = (unsigned short*)xzB;          // yh in x_proj half, pitch XZ_LD

    constexpr int SM1 = (3 * 256 * 32 + 3 * 256 * 32) * 2;   // 96 KiB
    constexpr int SM2 = (3 * 128 * 32 + 3 * 256 * 32) * 2;   // 72 KiB

    // 0) pack x, W_in -> bf16
    pack1_k<<<ROWS * D_MODEL / 4 / 256, 256, 0, stream>>>(
        (const float4*)x, (ushort4*)x1, ROWS * D_MODEL / 4);
    pack1_k<<<2 * D_INNER * D_MODEL / 4 / 256, 256, 0, stream>>>(
        (const float4*)W_in, (ushort4*)Wi1, 2 * D_INNER * D_MODEL / 4);
    // 1) xz = x @ W_in^T, bf16 output
    gemm8p<256, true><<<dim3(4096 / 256, ROWS / 256), 512, SM1, stream>>>(
        x1, D_MODEL, Wi1, D_MODEL, xz, XZ_LD, D_MODEL);
    // 2) conv + silu (bf16 in/out)
    conv_silu_k<<<ROWS * 512 / 256, 256, 0, stream>>>(xz, conv_w, conv_b, x_conv);
    // 3) x_proj -> fp32 params (r22 path: scan has zero param converts)
    proj_k<<<ROWS / 4, 256, 0, stream>>>(x_conv, W_xproj, A_log, Abar, Bbar, Cm);
    // 4) scan -> yh bf16 into xz rows' first half (pitch XZ_LD)
    scan_k<<<dim3(D_INNER / SCH, NB), 256, 0, stream>>>(
        x_conv, xz, yhl, Abar, Bbar, Cm, D_param);
    // 5) pack W_out -> bf16
    pack1_k<<<D_MODEL * D_INNER / 4 / 256, 256, 0, stream>>>(
        (const float4*)W_out, (ushort4*)Wo1, D_MODEL * D_INNER / 4);
    // 6) out = y @ W_out^T (fp32 output)
    gemm8p<128, false><<<dim3(1024 / 256, ROWS / 128), 512, SM2, stream>>>(
        yhl, XZ_LD, Wo1, D_INNER, out, D_MODEL, D_INNER);
}

// Round 25
// 461.640 us; speedup vs baseline: 1.1641x; 1.0072x over previous
//
#include <hip/hip_runtime.h>
#include <cmath>

#define D_MODEL 1024
#define D_STATE 16
#define D_INNER 2048
#define NB 4
#define SEQL 2048
#define ROWS (NB*SEQL)        // 8192
#define XZ_LD (2*D_INNER)     // 4096

typedef __attribute__((ext_vector_type(8))) short short8;
typedef __attribute__((ext_vector_type(4))) float f32x4;

__device__ __forceinline__ float sigmoidf_(float v) { return 1.0f / (1.0f + __expf(-v)); }

__device__ __forceinline__ unsigned short bf16rne(float f) {
    unsigned u = __float_as_uint(f);
    unsigned r = (u + 0x7FFFu + ((u >> 16) & 1u)) >> 16;
    return (unsigned short)r;
}
__device__ __forceinline__ float bf2f(unsigned short u) {
    return __uint_as_float((unsigned)u << 16);
}

// ---------------- fused fp32 -> bf16 pack of x, W_in, W_out (one launch) ----------------
// n1 = x float4 count (8192*1024/4 = 2097152 -> 8192 blocks)
// n2 = W_in count     (4096*1024/4 = 1048576 -> 4096 blocks)
// n3 = W_out count    (1024*2048/4 =  524288 -> 2048 blocks)
__global__ __launch_bounds__(256) void packAll_k(
    const float4* __restrict__ xin,  ushort4* __restrict__ xo,  int n1,
    const float4* __restrict__ win,  ushort4* __restrict__ wo,  int n2,
    const float4* __restrict__ uin,  ushort4* __restrict__ uo,  int n3)
{
    int i = blockIdx.x * 256 + threadIdx.x;
    const float4* src; ushort4* dst; int idx;
    if (i < n1)            { src = xin; dst = xo; idx = i; }
    else if (i < n1 + n2)  { src = win; dst = wo; idx = i - n1; }
    else if (i < n1 + n2 + n3) { src = uin; dst = uo; idx = i - n1 - n2; }
    else return;
    float4 v = src[idx];
    ushort4 h;
    h.x = bf16rne(v.x); h.y = bf16rne(v.y); h.z = bf16rne(v.z); h.w = bf16rne(v.w);
    dst[idx] = h;
}

// ============ 8-phase-style bf16 NT GEMM (round-10 schedule); OB -> bf16 C ============
#define GLDS(gp, lp) __builtin_amdgcn_global_load_lds( \
    (const __attribute__((address_space(1))) void*)(gp), \
    (__attribute__((address_space(3))) void*)(lp), 16, 0, 0)

extern __shared__ __align__(16) unsigned short smem8[];

template<int BM, bool OB>
__global__ __launch_bounds__(512, 2) void gemm8p(
    const unsigned short* __restrict__ A2, int lda,
    const unsigned short* __restrict__ B2, int ldb,
    void* __restrict__ Cv, int ldc, int K)
{
    constexpr int APAN = BM * 32;
    constexpr int BPAN = 256 * 32;
    constexpr int LA   = BM / 128;
    constexpr int MH   = BM / 128;
    constexpr int WROW = (BM == 256) ? 128 : 64;
    unsigned short* sA = smem8;
    unsigned short* sB = smem8 + 3 * APAN;

    const int tid = threadIdx.x;
    const int bm = blockIdx.y * BM, bn = blockIdx.x * 256;
    const int wave = tid >> 6, lane = tid & 63;
    const int wm = wave >> 2, wn = wave & 3;
    const int fr = lane & 15, kq = lane >> 4;
    const int NT = K >> 5;

    size_t offA[LA], offB[2];
#pragma unroll
    for (int i = 0; i < LA; ++i) {
        int c = i * 512 + tid;
        int row = c & (BM - 1), slot = (BM == 256) ? (c >> 8) : (c >> 7);
        offA[i] = (size_t)(bm + row) * lda + slot * 8;
    }
#pragma unroll
    for (int i = 0; i < 2; ++i) {
        int c = i * 512 + tid;
        int row = c & 255, slot = c >> 8;
        offB[i] = (size_t)(bn + row) * ldb + slot * 8;
    }

    auto stageA = [&](int s) {
        int ka = s * 32;
        unsigned short* d = sA + (s % 3) * APAN;
#pragma unroll
        for (int i = 0; i < LA; ++i)
            GLDS(A2 + offA[i] + ka, d + (i * 512 + tid) * 8);
    };
    auto stageB = [&](int s) {
        int kb = s * 32;
        unsigned short* d = sB + (s % 3) * BPAN;
#pragma unroll
        for (int i = 0; i < 2; ++i)
            GLDS(B2 + offB[i] + kb, d + (i * 512 + tid) * 8);
    };

    f32x4 acc[4 * MH][4];
#pragma unroll
    for (int m = 0; m < 4 * MH; ++m)
#pragma unroll
        for (int n = 0; n < 4; ++n) acc[m][n] = (f32x4){0.f, 0.f, 0.f, 0.f};

    stageA(0); stageB(0); stageA(1); stageB(1);
    if constexpr (BM == 256) asm volatile("s_waitcnt vmcnt(4)" ::: "memory");
    else                     asm volatile("s_waitcnt vmcnt(3)" ::: "memory");
    __builtin_amdgcn_s_barrier();
    asm volatile("" ::: "memory");

    for (int t = 0; t < NT; ++t) {
        const unsigned short* pA = sA + (t % 3) * APAN;
        const unsigned short* pB = sB + (t % 3) * BPAN;
        short8 b0[4], a0[4];
#pragma unroll
        for (int n = 0; n < 4; ++n)
            b0[n] = *(const short8*)&pB[(kq * 256 + wn * 64 + n * 16 + fr) * 8];
#pragma unroll
        for (int m = 0; m < 4; ++m)
            a0[m] = *(const short8*)&pA[(kq * BM + wm * WROW + m * 16 + fr) * 8];
        if (t + 2 < NT) stageA(t + 2);
        if constexpr (MH == 1) { if (t + 2 < NT) stageB(t + 2); }
        __builtin_amdgcn_s_barrier();
        asm volatile("" ::: "memory");
        __builtin_amdgcn_s_setprio(1);
#pragma unroll
        for (int m = 0; m < 4; ++m)
#pragma unroll
            for (int n = 0; n < 4; ++n)
                acc[m][n] = __builtin_amdgcn_mfma_f32_16x16x32_bf16(a0[m], b0[n], acc[m][n], 0, 0, 0);
        __builtin_amdgcn_s_setprio(0);
        if constexpr (MH == 2) {
            __builtin_amdgcn_s_barrier();
            asm volatile("" ::: "memory");
            short8 a1[4];
#pragma unroll
            for (int m = 0; m < 4; ++m)
                a1[m] = *(const short8*)&pA[(kq * 256 + wm * 128 + 64 + m * 16 + fr) * 8];
            if (t + 2 < NT) stageB(t + 2);
            __builtin_amdgcn_s_barrier();
            asm volatile("" ::: "memory");
            __builtin_amdgcn_s_setprio(1);
#pragma unroll
            for (int m = 0; m < 4; ++m)
#pragma unroll
                for (int n = 0; n < 4; ++n)
                    acc[4 + m][n] = __builtin_amdgcn_mfma_f32_16x16x32_bf16(a1[m], b0[n], acc[4 + m][n], 0, 0, 0);
            __builtin_amdgcn_s_setprio(0);
        }
        if (t + 2 < NT) {
            if constexpr (BM == 256) asm volatile("s_waitcnt vmcnt(4)" ::: "memory");
            else                     asm volatile("s_waitcnt vmcnt(3)" ::: "memory");
        } else if (t + 1 < NT) {
            asm volatile("s_waitcnt vmcnt(0)" ::: "memory");
        }
        __builtin_amdgcn_s_barrier();
        asm volatile("" ::: "memory");
    }

    // C/D layout: col = lane&15, row = (lane>>4)*4 + j
#pragma unroll
    for (int mm = 0; mm < 4 * MH; ++mm) {
        int row0 = bm + wm * WROW + mm * 16 + kq * 4;
#pragma unroll
        for (int j = 0; j < 4; ++j) {
            if constexpr (OB) {
                unsigned short* Cr = (unsigned short*)Cv + (size_t)(row0 + j) * ldc + bn + wn * 64 + fr;
#pragma unroll
                for (int n = 0; n < 4; ++n) Cr[n * 16] = bf16rne(acc[mm][n][j]);
            } else {
                float* Cr = (float*)Cv + (size_t)(row0 + j) * ldc + bn + wn * 64 + fr;
#pragma unroll
                for (int n = 0; n < 4; ++n) Cr[n * 16] = acc[mm][n][j];
            }
        }
    }
}

// ---------------- causal depthwise conv (D_CONV=4) + SiLU, bf16 in/out ----------------
__global__ __launch_bounds__(256) void conv_silu_k(
    const unsigned short* __restrict__ xz, const float* __restrict__ conv_w,
    const float* __restrict__ conv_b, unsigned short* __restrict__ x_conv)
{
    int idx = blockIdx.x * 256 + threadIdx.x;   // ROWS * 512 total
    int q = idx & 511;
    int r = idx >> 9;
    int b = r >> 11, t = r & (SEQL - 1);
    int d0 = q << 2;
    float w[4][4];
#pragma unroll
    for (int c = 0; c < 4; ++c) *(float4*)w[c] = *(const float4*)&conv_w[(d0 + c) * 4];
    float4 acc = *(const float4*)&conv_b[d0];
    const unsigned short* xp = xz + (size_t)(b * SEQL) * XZ_LD + d0;
#pragma unroll
    for (int k = 0; k < 4; ++k) {
        int t2 = t - 3 + k;
        if (t2 >= 0) {
            ushort4 v = *(const ushort4*)(xp + (size_t)t2 * XZ_LD);
            acc.x = fmaf(bf2f(v.x), w[0][k], acc.x);
            acc.y = fmaf(bf2f(v.y), w[1][k], acc.y);
            acc.z = fmaf(bf2f(v.z), w[2][k], acc.z);
            acc.w = fmaf(bf2f(v.w), w[3][k], acc.w);
        }
    }
    acc.x *= sigmoidf_(acc.x);
    acc.y *= sigmoidf_(acc.y);
    acc.z *= sigmoidf_(acc.z);
    acc.w *= sigmoidf_(acc.w);
    ushort4 hv;
    hv.x = bf16rne(acc.x); hv.y = bf16rne(acc.y);
    hv.z = bf16rne(acc.z); hv.w = bf16rne(acc.w);
    *(ushort4*)&x_conv[(size_t)r * D_INNER + d0] = hv;
}

// ---- x_proj (bf16 x_conv) -> A_bar/B_bar/C fp32, [row][s] layout ----
__global__ __launch_bounds__(256) void proj_k(
    const unsigned short* __restrict__ x_conv, const float* __restrict__ W_xproj,
    const float* __restrict__ A_log,
    float* __restrict__ Abar, float* __restrict__ Bbar, float* __restrict__ Cmat)
{
    __shared__ float sdbl[4][33];
    int tid = threadIdx.x;
    int w = tid >> 6, lane = tid & 63;
    int row = blockIdx.x * 4 + w;
    const unsigned short* xrow = x_conv + (size_t)row * D_INNER;
    float xf[32];
#pragma unroll
    for (int it = 0; it < 4; ++it) {
        short8 xv = *(const short8*)&xrow[it * 512 + lane * 8];
#pragma unroll
        for (int j = 0; j < 8; ++j)
            xf[it * 8 + j] = bf2f((unsigned short)xv[j]);
    }

    for (int j = 0; j < 33; ++j) {
        const float* wrow = W_xproj + j * D_INNER;
        float accv = 0.f;
#pragma unroll
        for (int it = 0; it < 4; ++it) {
            float4 w0 = *(const float4*)&wrow[it * 512 + lane * 8];
            float4 w1 = *(const float4*)&wrow[it * 512 + lane * 8 + 4];
            accv = fmaf(xf[it * 8 + 0], w0.x, accv);
            accv = fmaf(xf[it * 8 + 1], w0.y, accv);
            accv = fmaf(xf[it * 8 + 2], w0.z, accv);
            accv = fmaf(xf[it * 8 + 3], w0.w, accv);
            accv = fmaf(xf[it * 8 + 4], w1.x, accv);
            accv = fmaf(xf[it * 8 + 5], w1.y, accv);
            accv = fmaf(xf[it * 8 + 6], w1.z, accv);
            accv = fmaf(xf[it * 8 + 7], w1.w, accv);
        }
#pragma unroll
        for (int off = 32; off; off >>= 1) accv += __shfl_xor(accv, off);
        if (lane == 0) sdbl[w][j] = accv;
    }
    __syncthreads();
    if (tid < 64) {
        int w2 = tid >> 4, s = tid & 15;
        int row2 = blockIdx.x * 4 + w2;
        float draw = sdbl[w2][32];
        float sp = (draw > 20.f) ? draw : log1pf(__expf(draw));
        float dt = fminf(fmaxf(sp, 0.001f), 0.1f);
        float Aa = -__expf(A_log[s]);
        float dtA = fminf(fmaxf(dt * Aa, -20.f), 0.f);
        Abar[row2 * 16 + s] = __expf(dtA);
        float bb = dt * sdbl[w2][s];
        Bbar[row2 * 16 + s] = fminf(fmaxf(bb, -10.f), 10.f);
        Cmat[row2 * 16 + s] = sdbl[w2][16 + s];
    }
}

// ---------------- SSM scan: r24 structure (measured best: 171 us) ----------------
#define SCH 16
#define TT 16
__global__ __launch_bounds__(256) void scan_k(
    const unsigned short* __restrict__ x_conv, const unsigned short* __restrict__ xz,
    unsigned short* __restrict__ yhl,
    const float* __restrict__ Abar, const float* __restrict__ Bbar,
    const float* __restrict__ Cmat, const float* __restrict__ D_param)
{
    __shared__ __align__(16) unsigned short sXa[2][SCH][24];   // bf16 x
    __shared__ float sZp[2][SCH][17];                          // z fp32
    __shared__ __align__(16) float sPa[2][16][20];             // A fp32
    __shared__ __align__(16) float sPb[2][16][20];             // B fp32
    __shared__ __align__(16) float sPc[2][16][20];             // C fp32
    __shared__ __align__(16) float sT[SCH][328];

    const int tid = threadIdx.x;
    const int b = blockIdx.y, dbase = blockIdx.x * SCH;
    const int chl = tid >> 4, s = tid & 15;
    const unsigned short* xc = x_conv + (size_t)(b * SEQL) * D_INNER + dbase;
    const unsigned short* zp = xz + (size_t)(b * SEQL) * XZ_LD + D_INNER + dbase;
    const int pbase0 = (b * SEQL) * 16;
    const int st = tid >> 4, sc = tid & 15;

    auto stage = [&](int buf, int tc) {
        int t0 = tc * TT;
        sXa[buf][sc][st] = xc[(size_t)(t0 + st) * D_INNER + sc];
        sZp[buf][sc][st] = bf2f(zp[(size_t)(t0 + st) * XZ_LD + sc]);
        int g = pbase0 + t0 * 16 + tid;
        sPa[buf][sc][st] = Abar[g];
        sPb[buf][sc][st] = Bbar[g];
        sPc[buf][sc][st] = Cmat[g];
    };

    stage(0, 0);
    float h = 0.f;
    const float Dp = D_param[dbase + chl];

    for (int tc = 0; tc < SEQL / TT; ++tc) {
        int buf = tc & 1;
        int t0 = tc * TT;
        __syncthreads();
        if (tc + 1 < SEQL / TT) stage(buf ^ 1, tc + 1);

        float p[16];
#pragma unroll
        for (int q = 0; q < 4; ++q) {
            float4 a4 = *(const float4*)&sPa[buf][s][q * 4];
            float4 b4 = *(const float4*)&sPb[buf][s][q * 4];
            float4 c4 = *(const float4*)&sPc[buf][s][q * 4];
            ushort4 xu = *(const ushort4*)&sXa[buf][chl][q * 4];
            float x0 = bf2f(xu.x), x1 = bf2f(xu.y), x2 = bf2f(xu.z), x3 = bf2f(xu.w);
            h = fminf(fmaxf(fmaf(b4.x, x0, a4.x * h), -100.f), 100.f); p[q * 4 + 0] = h * c4.x;
            h = fminf(fmaxf(fmaf(b4.y, x1, a4.y * h), -100.f), 100.f); p[q * 4 + 1] = h * c4.y;
            h = fminf(fmaxf(fmaf(b4.z, x2, a4.z * h), -100.f), 100.f); p[q * 4 + 2] = h * c4.z;
            h = fminf(fmaxf(fmaf(b4.w, x3, a4.w * h), -100.f), 100.f); p[q * 4 + 3] = h * c4.w;
        }

#pragma unroll
        for (int i = 0; i < 16; ++i) sT[chl][i * 20 + s] = p[i];
        float4 r0 = *(const float4*)&sT[chl][s * 20 + 0];
        float4 r1 = *(const float4*)&sT[chl][s * 20 + 4];
        float4 r2 = *(const float4*)&sT[chl][s * 20 + 8];
        float4 r3 = *(const float4*)&sT[chl][s * 20 + 12];
        float ysum = ((r0.x + r1.x + r2.x + r3.x) + (r0.y + r1.y + r2.y + r3.y))
                   + ((r0.z + r1.z + r2.z + r3.z) + (r0.w + r1.w + r2.w + r3.w));

        float z = sZp[buf][chl][s];
        float x = bf2f(sXa[buf][chl][s]);
        float o = fmaf(x, Dp, ysum * (z * sigmoidf_(z)));
        size_t r = (size_t)(b * SEQL + t0 + s);
        yhl[r * XZ_LD + dbase + chl] = bf16rne(o);
    }
}

extern "C" void kernel_launch(void* const* d_in, const int* in_sizes, int n_in,
                              void* d_out, int out_size, void* d_ws, size_t ws_size,
                              hipStream_t stream) {
    const float* x       = (const float*)d_in[0];
    const float* W_in    = (const float*)d_in[1];
    const float* conv_w  = (const float*)d_in[2];
    const float* conv_b  = (const float*)d_in[3];
    const float* W_xproj = (const float*)d_in[4];
    const float* A_log   = (const float*)d_in[5];
    const float* D_param = (const float*)d_in[6];
    const float* W_out   = (const float*)d_in[7];
    float* out = (float*)d_out;

    // ---- workspace: round-1 footprint (202.9 MB), phase-aliased ----
    char* p = (char*)d_ws;
    char* xzB = p;
    unsigned short* xz = (unsigned short*)xzB;   // bf16 xz: ROWS x XZ_LD ushorts (67 MB)
    p += (size_t)ROWS * XZ_LD * 4;               // region reserved at fp32 size
    char* xcB = p;
    unsigned short* x_conv = (unsigned short*)xcB;   // 33.5 MB bf16
    p += (size_t)ROWS * D_INNER * 4;
    float* Abar = (float*)p; p += (size_t)ROWS * 16 * 4;
    float* Bbar = (float*)p; p += (size_t)ROWS * 16 * 4;
    float* Cm   = (float*)p; p += (size_t)ROWS * 16 * 4;

    unsigned short* x1  = (unsigned short*)xcB;          // [0, 16.8 MB)   dead after GEMM1
    unsigned short* Wi1 = x1 + (size_t)ROWS * D_MODEL;   // [16.8, 25.2)   dead after GEMM1
    unsigned short* Wo1 = x1 + (size_t)ROWS * D_INNER;   // [33.5, 37.7)   disjoint from all
    unsigned short* yhl = (unsigned short*)xzB;          // yh in x_proj half, pitch XZ_LD

    constexpr int SM1 = (3 * 256 * 32 + 3 * 256 * 32) * 2;   // 96 KiB
    constexpr int SM2 = (3 * 128 * 32 + 3 * 256 * 32) * 2;   // 72 KiB

    constexpr int N1 = ROWS * D_MODEL / 4;             // x float4s
    constexpr int N2 = 2 * D_INNER * D_MODEL / 4;      // W_in
    constexpr int N3 = D_MODEL * D_INNER / 4;          // W_out

    // 0) single fused pack: x, W_in, W_out -> bf16 (W_out front-loaded; its region is
    //    disjoint from x1/Wi1/x_conv/xz so it survives until GEMM2)
    packAll_k<<<(N1 + N2 + N3) / 256, 256, 0, stream>>>(
        (const float4*)x, (ushort4*)x1, N1,
        (const float4*)W_in, (ushort4*)Wi1, N2,
        (const float4*)W_out, (ushort4*)Wo1, N3);
    // 1) xz = x @ W_in^T, bf16 output
    gemm8p<256, true><<<dim3(4096 / 256, ROWS / 256), 512, SM1, stream>>>(
        x1, D_MODEL, Wi1, D_MODEL, xz, XZ_LD, D_MODEL);
    // 2) conv + silu (bf16 in/out)
    conv_silu_k<<<ROWS * 512 / 256, 256, 0, stream>>>(xz, conv_w, conv_b, x_conv);
    // 3) x_proj -> fp32 params
    proj_k<<<ROWS / 4, 256, 0, stream>>>(x_conv, W_xproj, A_log, Abar, Bbar, Cm);
    // 4) scan -> yh bf16 into xz rows' first half (pitch XZ_LD)
    scan_k<<<dim3(D_INNER / SCH, NB), 256, 0, stream>>>(
        x_conv, xz, yhl, Abar, Bbar, Cm, D_param);
    // 5) out = y @ W_out^T (fp32 output)
    gemm8p<128, false><<<dim3(1024 / 256, ROWS / 128), 512, SM2, stream>>>(
        yhl, XZ_LD, Wo1, D_INNER, out, D_MODEL, D_INNER);
}